// Round 1
// baseline (205.544 us; speedup 1.0000x reference)
//
#include <hip/hip_runtime.h>

// MultiHeadAttention: B=2, S=2048, D=1024, H=16, hd=64. fp32 I/O.
// Round 17: attention goes to 8-wave (512-thread) blocks with k-tile
// PARITY split: waves w&3 keep their 16-row q-slice, w>>2 picks even/odd
// k-tiles; partial (acc,l) pairs combine through LDS at the end. This
// doubles resident waves/CU (8 -> 16, occupancy cap 25% -> 50%) while
// preserving the balanced {p, 31-p} pairing. K staged by waves 0-3,
// V by waves 4-7. KTPB 3 -> 2 (LDS 50KB, 2 blocks/CU, capacity 3).
// GEMMs unchanged from R16 (191us best).

typedef __attribute__((ext_vector_type(8))) short short8;
typedef __attribute__((ext_vector_type(4))) float floatx4;

__device__ inline unsigned short f2bf(float f) {
  unsigned u = __float_as_uint(f);
  unsigned r = (u + 0x7fffu + ((u >> 16) & 1u)) >> 16;  // RNE
  return (unsigned short)r;
}

__device__ __forceinline__ float fast_exp2(float x) {
#if __has_builtin(__builtin_amdgcn_exp2f)
  return __builtin_amdgcn_exp2f(x);
#else
  float r;
  asm volatile("v_exp_f32_e32 %0, %1" : "=v"(r) : "v"(x));
  return r;
#endif
}

__device__ __forceinline__ void gll16(const unsigned short* g, unsigned short* l) {
  __builtin_amdgcn_global_load_lds(
      (const __attribute__((address_space(1))) unsigned int*)(g),
      (__attribute__((address_space(3))) unsigned int*)(l),
      16, 0, 0);
}

constexpr int B_ = 2, S_ = 2048, D_ = 1024, H_ = 16, HD_ = 64;

// ---------------------------------------------------------------------------
// Merged one-time converter: z=0..3 -> W transpose+convert; z=4 -> X convert.
// ---------------------------------------------------------------------------
__global__ __launch_bounds__(256) void prep_inputs(
    const float* __restrict__ x, unsigned short* __restrict__ xb,
    const float* __restrict__ w0, const float* __restrict__ w1,
    const float* __restrict__ w2, const float* __restrict__ w3,
    unsigned short* __restrict__ wt_base)
{
  if (blockIdx.z == 4) {
    const int tid = threadIdx.y * 32 + threadIdx.x;
    const size_t base =
        ((size_t)(blockIdx.y * 32 + blockIdx.x) * 256 + tid) * 16;
#pragma unroll
    for (int half = 0; half < 2; ++half) {
      const size_t i = base + half * 8;
      float4 a = *(const float4*)(x + i);
      float4 b = *(const float4*)(x + i + 4);
      short8 o;
      o[0] = (short)f2bf(a.x); o[1] = (short)f2bf(a.y);
      o[2] = (short)f2bf(a.z); o[3] = (short)f2bf(a.w);
      o[4] = (short)f2bf(b.x); o[5] = (short)f2bf(b.y);
      o[6] = (short)f2bf(b.z); o[7] = (short)f2bf(b.w);
      *(short8*)(xb + i) = o;
    }
    return;
  }
  const float* src;
  switch (blockIdx.z) {
    case 0: src = w0; break;
    case 1: src = w1; break;
    case 2: src = w2; break;
    default: src = w3; break;
  }
  unsigned short* dst = wt_base + (size_t)blockIdx.z * 1024 * 1024;
  __shared__ unsigned short t[32][33];
  const int bx = blockIdx.x * 32;  // n
  const int by = blockIdx.y * 32;  // k
  const int x_ = threadIdx.x;
  for (int yy = threadIdx.y; yy < 32; yy += 8)
    t[yy][x_] = f2bf(src[(size_t)(by + yy) * 1024 + bx + x_]);
  __syncthreads();
  for (int yy = threadIdx.y; yy < 32; yy += 8)
    dst[(size_t)(bx + yy) * 1024 + by + x_] = t[x_][yy];
}

// Vb[b][s][h*64+d] bf16 -> Vt[(b*16+h)*64+d][s] bf16
__global__ __launch_bounds__(256) void transpose_v(
    const unsigned short* __restrict__ Vb, unsigned short* __restrict__ Vt)
{
  __shared__ unsigned short t[32][33];
  const int bh = blockIdx.z;
  const int b = bh >> 4, h = bh & 15;
  const int s0 = blockIdx.x * 32, d0 = blockIdx.y * 32;
  const int x = threadIdx.x;
  for (int yy = threadIdx.y; yy < 32; yy += 8)
    t[yy][x] = Vb[(size_t)(b * 2048 + s0 + yy) * 1024 + h * 64 + d0 + x];
  __syncthreads();
  for (int yy = threadIdx.y; yy < 32; yy += 8)
    Vt[((size_t)bh * 64 + d0 + yy) * 2048 + s0 + x] = t[x][yy];
}

// ---------------------------------------------------------------------------
// QKV GEMM (unchanged): 128x128 tile, BK=64 two-subtile staging.
// ---------------------------------------------------------------------------
__global__ __launch_bounds__(256) void gemm256_qkv(
    const unsigned short* __restrict__ A,
    const unsigned short* __restrict__ Bt,
    unsigned short* __restrict__ Qo,
    unsigned short* __restrict__ Ko,
    unsigned short* __restrict__ Vo)
{
  __shared__ unsigned short sA[2][128 * 32];
  __shared__ unsigned short sB[2][128 * 32];
  const int K = 1024;
  const int m0 = blockIdx.y * 128;
  const int bn0 = blockIdx.x * 128;

  const int tid = threadIdx.x, wave = tid >> 6, lane = tid & 63;
  const int g = lane >> 4, ml = lane & 15;
  const int wm = wave & 1, wn = wave >> 1;

  const unsigned short* ag0 = A + (size_t)(m0 + (tid >> 2)) * K + (tid & 3) * 8;
  const unsigned short* ag1 = ag0 + (size_t)64 * K;
  const unsigned short* bg0 = Bt + (size_t)(bn0 + (tid >> 2)) * K + (tid & 3) * 8;
  const unsigned short* bg1 = bg0 + (size_t)64 * K;
  const int woff = wave * 512;

  floatx4 acc[4][4];
#pragma unroll
  for (int mt = 0; mt < 4; ++mt)
#pragma unroll
    for (int nt = 0; nt < 4; ++nt) acc[mt][nt] = (floatx4){0.f, 0.f, 0.f, 0.f};

  for (int k0 = 0; k0 < K; k0 += 64) {
    __syncthreads();
#pragma unroll
    for (int t = 0; t < 2; ++t) {
      gll16(ag0 + k0 + t * 32, sA[t] + woff);
      gll16(ag1 + k0 + t * 32, sA[t] + 2048 + woff);
      gll16(bg0 + k0 + t * 32, sB[t] + woff);
      gll16(bg1 + k0 + t * 32, sB[t] + 2048 + woff);
    }
    __syncthreads();
#pragma unroll
    for (int t = 0; t < 2; ++t) {
      short8 af[4], bf[4];
#pragma unroll
      for (int mt = 0; mt < 4; ++mt)
        af[mt] = *(const short8*)(sA[t] + (wm * 64 + mt * 16 + ml) * 32 + g * 8);
#pragma unroll
      for (int nt = 0; nt < 4; ++nt)
        bf[nt] = *(const short8*)(sB[t] + (wn * 64 + nt * 16 + ml) * 32 + g * 8);
#pragma unroll
      for (int mt = 0; mt < 4; ++mt)
#pragma unroll
        for (int nt = 0; nt < 4; ++nt)
          acc[mt][nt] = __builtin_amdgcn_mfma_f32_16x16x32_bf16(
              af[mt], bf[nt], acc[mt][nt], 0, 0, 0);
    }
  }

  const int proj = blockIdx.x >> 3;
  unsigned short* out = (proj == 0) ? Qo : (proj == 1) ? Ko : Vo;
  const int col0 = (blockIdx.x & 7) * 128;
#pragma unroll
  for (int mt = 0; mt < 4; ++mt) {
#pragma unroll
    for (int nt = 0; nt < 4; ++nt) {
      const int col = col0 + wn * 64 + nt * 16 + ml;
#pragma unroll
      for (int r = 0; r < 4; ++r) {
        const int row = m0 + wm * 64 + mt * 16 + g * 4 + r;
        out[(size_t)row * 1024 + col] = f2bf(acc[mt][nt][r]);
      }
    }
  }
}

// Output projection, 64x128 tile, BK=128 four-subtile staging (8 stages).
__global__ __launch_bounds__(256) void gemm_wo64(
    const unsigned short* __restrict__ A,
    const unsigned short* __restrict__ Bt,
    const float* __restrict__ bias,
    float* __restrict__ C)
{
  __shared__ unsigned short sA[4][64 * 32];
  __shared__ unsigned short sB[4][128 * 32];
  const int K = 1024;
  const int m0 = blockIdx.y * 64;
  const int bn0 = blockIdx.x * 128;
  const int tid = threadIdx.x, wave = tid >> 6, lane = tid & 63;
  const int g = lane >> 4, ml = lane & 15;
  const int wm = wave & 1, wn = wave >> 1;

  const unsigned short* ag =
      A + (size_t)(m0 + wave * 16 + (lane >> 2)) * K + (lane & 3) * 8;
  const unsigned short* bg0 = Bt + (size_t)(bn0 + (tid >> 2)) * K + (tid & 3) * 8;
  const unsigned short* bg1 = bg0 + (size_t)64 * K;
  const int woff = wave * 512;

  floatx4 acc[2][4];
#pragma unroll
  for (int mt = 0; mt < 2; ++mt)
#pragma unroll
    for (int nt = 0; nt < 4; ++nt) acc[mt][nt] = (floatx4){0.f, 0.f, 0.f, 0.f};

  for (int k0 = 0; k0 < K; k0 += 128) {
    __syncthreads();
#pragma unroll
    for (int t = 0; t < 4; ++t) {
      gll16(ag + k0 + t * 32, sA[t] + woff);
      gll16(bg0 + k0 + t * 32, sB[t] + woff);
      gll16(bg1 + k0 + t * 32, sB[t] + 2048 + woff);
    }
    __syncthreads();
#pragma unroll
    for (int t = 0; t < 4; ++t) {
      short8 af[2], bf[4];
#pragma unroll
      for (int mt = 0; mt < 2; ++mt)
        af[mt] = *(const short8*)(sA[t] + (wm * 32 + mt * 16 + ml) * 32 + g * 8);
#pragma unroll
      for (int nt = 0; nt < 4; ++nt)
        bf[nt] = *(const short8*)(sB[t] + (wn * 64 + nt * 16 + ml) * 32 + g * 8);
#pragma unroll
      for (int mt = 0; mt < 2; ++mt)
#pragma unroll
        for (int nt = 0; nt < 4; ++nt)
          acc[mt][nt] = __builtin_amdgcn_mfma_f32_16x16x32_bf16(
              af[mt], bf[nt], acc[mt][nt], 0, 0, 0);
    }
  }

#pragma unroll
  for (int mt = 0; mt < 2; ++mt) {
#pragma unroll
    for (int nt = 0; nt < 4; ++nt) {
      const int col = bn0 + wn * 64 + nt * 16 + ml;
      const float badd = bias[col];
#pragma unroll
      for (int r = 0; r < 4; ++r) {
        const int row = m0 + wm * 32 + mt * 16 + g * 4 + r;
        C[(size_t)row * 1024 + col] = acc[mt][nt][r] + badd;
      }
    }
  }
}

// ---------------------------------------------------------------------------
// Attention v11: 8-wave blocks, k-tile parity split.
//   wave w: slice = w&3 (16-row q-slice, same rows as v10's wave), par = w>>2.
//   Waves 0-3 stage K tiles, waves 4-7 stage V tiles (2 gll16 each per tile).
//   Each barrier stages KTPB=2 tiles; wave with parity p computes tile p
//   for q-block B and (if in causal range) q-block A.
//   Pair (w, w+4) partial acc/l combined through LDS at the end.
// LDS = 4*2*4KB (K/V dbuf) + 8*16*LDP*2 (sP) = 50KB -> 2 blocks/CU at
// grid 512 -> 16 waves/CU (occupancy cap 25% -> 50%).
// ---------------------------------------------------------------------------
constexpr int LDP = 72;
constexpr int KTPB = 2;  // k-tiles per barrier

struct AttnLds {
  unsigned short k0[KTPB][64 * 32];
  unsigned short k1[KTPB][64 * 32];
  unsigned short v0[KTPB][64 * 32];
  unsigned short v1[KTPB][64 * 32];
  unsigned short p[8 * 16 * LDP];
};
union __align__(16) AttnLdsU {
  AttnLds t;
  float comb[4 * 64 * 40];  // 40.96KB <= sizeof(AttnLds)=51.2KB
};

__device__ __forceinline__ void attn_tile(
    const short8* aq,
    const unsigned short* sK0, const unsigned short* sK1,
    const unsigned short* sV0, const unsigned short* sV1,
    unsigned short* pw, floatx4* acc, float* l,
    const bool diag, const int qrow0, const int kcol0,
    const int g, const int ml)
{
  const float C1 = 0.18033688f;    // 0.125 / ln2
  const float C2 = -34.6246810f;   // -24 / ln2

  floatx4 s[4];
#pragma unroll
  for (int nb = 0; nb < 4; ++nb) {
    s[nb] = (floatx4){0.f, 0.f, 0.f, 0.f};
    short8 bk0 = *(const short8*)(sK0 + (nb * 16 + ml) * 32 + g * 8);
    s[nb] = __builtin_amdgcn_mfma_f32_16x16x32_bf16(aq[0], bk0, s[nb], 0, 0, 0);
    short8 bk1 = *(const short8*)(sK1 + (nb * 16 + ml) * 32 + g * 8);
    s[nb] = __builtin_amdgcn_mfma_f32_16x16x32_bf16(aq[1], bk1, s[nb], 0, 0, 0);
  }
#pragma unroll
  for (int r = 0; r < 4; ++r) {
    const int qrow = qrow0 + g * 4 + r;
    float rowsum = 0.f;
#pragma unroll
    for (int nb = 0; nb < 4; ++nb) {
      float wv = fast_exp2(fmaf(s[nb][r], C1, C2));
      if (diag && (kcol0 + nb * 16 + ml > qrow)) wv = 0.f;
      const unsigned bits = __float_as_uint(wv);
      pw[(g * 4 + r) * LDP + nb * 16 + ml] = (unsigned short)(bits >> 16);
      rowsum += __uint_as_float(bits & 0xffff0000u);
    }
    l[r] += rowsum;
  }
#pragma unroll
  for (int st = 0; st < 2; ++st) {
    short8 ap = *(const short8*)(pw + ml * LDP + st * 32 + g * 8);
    const unsigned short* sv = st ? sV1 : sV0;
#pragma unroll
    for (int jd = 0; jd < 4; ++jd) {
      short8 bv = *(const short8*)(sv + (jd * 16 + ml) * 32 + g * 8);
      acc[jd] = __builtin_amdgcn_mfma_f32_16x16x32_bf16(ap, bv, acc[jd], 0, 0, 0);
    }
  }
}

__global__ __launch_bounds__(512) void attn_v11(
    const unsigned short* __restrict__ Q,
    const unsigned short* __restrict__ Kg,
    const unsigned short* __restrict__ Vt,
    unsigned short* __restrict__ CTX)
{
  __shared__ AttnLdsU lds;

  const int bh = blockIdx.y;
  const int b = bh >> 4, h = bh & 15;
  const int p = blockIdx.x;
  const int qbA = p, qbB = 31 - p;
  const int qA0 = qbA * 64, qB0 = qbB * 64;
  const int tid = threadIdx.x, w = tid >> 6, lane = tid & 63;
  const int slice = w & 3, par = w >> 2;
  const int g = lane >> 4, ml = lane & 15;

  const size_t headoff = (size_t)b * S_ * D_ + (size_t)h * HD_;
  const size_t vtoff   = (size_t)bh * HD_ * S_;

  short8 aqA[2], aqB[2];
  {
    const unsigned short* qp =
        Q + headoff + (size_t)(qA0 + slice * 16 + ml) * D_ + g * 8;
    aqA[0] = *(const short8*)qp;
    aqA[1] = *(const short8*)(qp + 32);
  }
  {
    const unsigned short* qp =
        Q + headoff + (size_t)(qB0 + slice * 16 + ml) * D_ + g * 8;
    aqB[0] = *(const short8*)qp;
    aqB[1] = *(const short8*)(qp + 32);
  }

  floatx4 accA[4], accB[4];
#pragma unroll
  for (int jd = 0; jd < 4; ++jd) {
    accA[jd] = (floatx4){0.f, 0.f, 0.f, 0.f};
    accB[jd] = (floatx4){0.f, 0.f, 0.f, 0.f};
  }
  float lA[4] = {0.f, 0.f, 0.f, 0.f};
  float lB[4] = {0.f, 0.f, 0.f, 0.f};

  // staging: waves 0-3 handle K, waves 4-7 handle V; each covers 16 rows.
  const int sw = slice;
  const unsigned short* kgb =
      Kg + headoff + (size_t)(sw * 16 + (lane >> 2)) * D_ + (lane & 3) * 8;
  const unsigned short* vgb =
      Vt + vtoff + (size_t)(sw * 16 + (lane >> 2)) * S_ + (lane & 3) * 8;
  unsigned short* pw = lds.t.p + w * 16 * LDP;
  const int woff = sw * 512;

  const int ntiles = qbB + 1;
  for (int kt0 = 0; kt0 < ntiles; kt0 += KTPB) {
    const int cnt = (ntiles - kt0 < KTPB) ? (ntiles - kt0) : KTPB;  // uniform
    __syncthreads();
#pragma unroll
    for (int t = 0; t < KTPB; ++t) {
      if (t >= cnt) break;
      const int kt = kt0 + t;
      if (w < 4) {
        const size_t ko = (size_t)kt * 64 * D_;
        gll16(kgb + ko,      lds.t.k0[t] + woff);
        gll16(kgb + ko + 32, lds.t.k1[t] + woff);
      } else {
        gll16(vgb + kt * 64,      lds.t.v0[t] + woff);
        gll16(vgb + kt * 64 + 32, lds.t.v1[t] + woff);
      }
    }
    __syncthreads();

    if (par < cnt) {
      const int kt = kt0 + par;
      attn_tile(aqB, lds.t.k0[par], lds.t.k1[par], lds.t.v0[par], lds.t.v1[par],
                pw, accB, lB, kt == qbB, qB0 + slice * 16, kt * 64, g, ml);
      if (kt <= qbA)
        attn_tile(aqA, lds.t.k0[par], lds.t.k1[par], lds.t.v0[par], lds.t.v1[par],
                  pw, accA, lA, kt == qbA, qA0 + slice * 16, kt * 64, g, ml);
    }
  }

  // ---- combine parity pairs (w, w+4) through LDS ----
  __syncthreads();
  {
    float* slot = lds.comb + (size_t)(slice * 64 + lane) * 40;
    if (par == 1) {
#pragma unroll
      for (int jd = 0; jd < 4; ++jd) {
        *(floatx4*)(slot + jd * 4) = accA[jd];
        *(floatx4*)(slot + 20 + jd * 4) = accB[jd];
      }
#pragma unroll
      for (int r = 0; r < 4; ++r) {
        slot[16 + r] = lA[r];
        slot[36 + r] = lB[r];
      }
    }
    __syncthreads();
    if (par == 1) return;  // upper waves done; no further barriers below
#pragma unroll
    for (int jd = 0; jd < 4; ++jd) {
      accA[jd] += *(const floatx4*)(slot + jd * 4);
      accB[jd] += *(const floatx4*)(slot + 20 + jd * 4);
    }
#pragma unroll
    for (int r = 0; r < 4; ++r) {
      lA[r] += slot[16 + r];
      lB[r] += slot[36 + r];
    }
  }

#pragma unroll
  for (int r = 0; r < 4; ++r) {
    float la = lA[r];
    la += __shfl_xor(la, 1); la += __shfl_xor(la, 2);
    la += __shfl_xor(la, 4); la += __shfl_xor(la, 8);
    lA[r] = 1.0f / la;
    float lb = lB[r];
    lb += __shfl_xor(lb, 1); lb += __shfl_xor(lb, 2);
    lb += __shfl_xor(lb, 4); lb += __shfl_xor(lb, 8);
    lB[r] = 1.0f / lb;
  }
#pragma unroll
  for (int r = 0; r < 4; ++r) {
    const int rowA = qA0 + slice * 16 + g * 4 + r;
    const int rowB = qB0 + slice * 16 + g * 4 + r;
#pragma unroll
    for (int jd = 0; jd < 4; ++jd) {
      CTX[headoff + (size_t)rowA * D_ + jd * 16 + ml] = f2bf(accA[jd][r] * lA[r]);
      CTX[headoff + (size_t)rowB * D_ + jd * 16 + ml] = f2bf(accB[jd][r] * lB[r]);
    }
  }
}

// ---------------------------------------------------------------------------
extern "C" void kernel_launch(void* const* d_in, const int* in_sizes, int n_in,
                              void* d_out, int out_size, void* d_ws, size_t ws_size,
                              hipStream_t stream)
{
  const float* X  = (const float*)d_in[0];
  const float* Wq = (const float*)d_in[1];
  const float* Wk = (const float*)d_in[2];
  const float* Wv = (const float*)d_in[3];
  const float* Wo = (const float*)d_in[4];
  const float* bo = (const float*)d_in[5];

  char* ws = (char*)d_ws;
  const size_t MB = 1024 * 1024;

  unsigned short* Qb  = (unsigned short*)(ws);            // 8 MB (CTX aliases)
  unsigned short* Kb  = (unsigned short*)(ws + 8 * MB);   // 8 MB
  unsigned short* Xb  = (unsigned short*)(ws + 16 * MB);  // 8 MB; Vt after QKV
  unsigned short* WT  = (unsigned short*)(ws + 24 * MB);  // WqT|WkT|WvT|WoT
  unsigned short* WoT = WT + (size_t)3 * 1024 * 1024;
  unsigned short* Vb  = (unsigned short*)d_out;           // low 8MB of d_out
  unsigned short* Vt  = Xb;                               // reuse dead Xb

  // merged X-convert (z=4) + 4x W transpose/convert (z=0..3)
  prep_inputs<<<dim3(32, 32, 5), dim3(32, 8), 0, stream>>>(
      X, Xb, Wq, Wk, Wv, Wo, WT);
  // fused Q/K/V projection: Bt = WT[0..3071][1024], BK=64 staging
  gemm256_qkv<<<dim3(24, 32), 256, 0, stream>>>(Xb, WT, Qb, Kb, Vb);
  // V -> Vt[(b*16+h)*64+d][s]  (Xb dead now)
  transpose_v<<<dim3(64, 2, 32), dim3(32, 8), 0, stream>>>(Vb, Vt);
  // 8-wave parity-split attention; CTX aliases Q
  attn_v11<<<dim3(16, B_ * H_), 512, 0, stream>>>(Qb, Kb, Vt, Qb);
  // output projection + bias (64x128 tile, BK=128, 512 blocks)
  gemm_wo64<<<dim3(8, 64), 256, 0, stream>>>(Qb, WoT, bo, (float*)d_out);
}

// Round 2
// 201.085 us; speedup vs baseline: 1.0222x; 1.0222x over previous
//
#include <hip/hip_runtime.h>

// MultiHeadAttention: B=2, S=2048, D=1024, H=16, hd=64. fp32 I/O.
// Round 18: attention softmax goes FULLY IN-REGISTER (T12 pattern):
// swapped QK^T (mfma(K,Q)) makes q lane-local (q=ml); P stays in VGPRs,
// redistributed into the PV A-fragment with 2x v_permlane32_swap +
// 2x v_permlane16_swap per rr (8 permlane + 8 v_perm per tile), replacing
// 16 ds_write_u16 + 2 ds_read_b128 + 2 LDS latencies + P bank conflicts.
// Truncated-bf16 P semantics preserved exactly (v_perm picks bytes 2,3).
// sP deleted: LDS 51.2 -> 36.9 KB. Everything else = R17 structure.

typedef __attribute__((ext_vector_type(8))) short short8;
typedef __attribute__((ext_vector_type(4))) float floatx4;

__device__ inline unsigned short f2bf(float f) {
  unsigned u = __float_as_uint(f);
  unsigned r = (u + 0x7fffu + ((u >> 16) & 1u)) >> 16;  // RNE
  return (unsigned short)r;
}

__device__ __forceinline__ float fast_exp2(float x) {
#if __has_builtin(__builtin_amdgcn_exp2f)
  return __builtin_amdgcn_exp2f(x);
#else
  float r;
  asm volatile("v_exp_f32_e32 %0, %1" : "=v"(r) : "v"(x));
  return r;
#endif
}

__device__ __forceinline__ void gll16(const unsigned short* g, unsigned short* l) {
  __builtin_amdgcn_global_load_lds(
      (const __attribute__((address_space(1))) unsigned int*)(g),
      (__attribute__((address_space(3))) unsigned int*)(l),
      16, 0, 0);
}

constexpr int B_ = 2, S_ = 2048, D_ = 1024, H_ = 16, HD_ = 64;

// ---------------------------------------------------------------------------
// Merged one-time converter: z=0..3 -> W transpose+convert; z=4 -> X convert.
// ---------------------------------------------------------------------------
__global__ __launch_bounds__(256) void prep_inputs(
    const float* __restrict__ x, unsigned short* __restrict__ xb,
    const float* __restrict__ w0, const float* __restrict__ w1,
    const float* __restrict__ w2, const float* __restrict__ w3,
    unsigned short* __restrict__ wt_base)
{
  if (blockIdx.z == 4) {
    const int tid = threadIdx.y * 32 + threadIdx.x;
    const size_t base =
        ((size_t)(blockIdx.y * 32 + blockIdx.x) * 256 + tid) * 16;
#pragma unroll
    for (int half = 0; half < 2; ++half) {
      const size_t i = base + half * 8;
      float4 a = *(const float4*)(x + i);
      float4 b = *(const float4*)(x + i + 4);
      short8 o;
      o[0] = (short)f2bf(a.x); o[1] = (short)f2bf(a.y);
      o[2] = (short)f2bf(a.z); o[3] = (short)f2bf(a.w);
      o[4] = (short)f2bf(b.x); o[5] = (short)f2bf(b.y);
      o[6] = (short)f2bf(b.z); o[7] = (short)f2bf(b.w);
      *(short8*)(xb + i) = o;
    }
    return;
  }
  const float* src;
  switch (blockIdx.z) {
    case 0: src = w0; break;
    case 1: src = w1; break;
    case 2: src = w2; break;
    default: src = w3; break;
  }
  unsigned short* dst = wt_base + (size_t)blockIdx.z * 1024 * 1024;
  __shared__ unsigned short t[32][33];
  const int bx = blockIdx.x * 32;  // n
  const int by = blockIdx.y * 32;  // k
  const int x_ = threadIdx.x;
  for (int yy = threadIdx.y; yy < 32; yy += 8)
    t[yy][x_] = f2bf(src[(size_t)(by + yy) * 1024 + bx + x_]);
  __syncthreads();
  for (int yy = threadIdx.y; yy < 32; yy += 8)
    dst[(size_t)(bx + yy) * 1024 + by + x_] = t[x_][yy];
}

// Vb[b][s][h*64+d] bf16 -> Vt[(b*16+h)*64+d][s] bf16
__global__ __launch_bounds__(256) void transpose_v(
    const unsigned short* __restrict__ Vb, unsigned short* __restrict__ Vt)
{
  __shared__ unsigned short t[32][33];
  const int bh = blockIdx.z;
  const int b = bh >> 4, h = bh & 15;
  const int s0 = blockIdx.x * 32, d0 = blockIdx.y * 32;
  const int x = threadIdx.x;
  for (int yy = threadIdx.y; yy < 32; yy += 8)
    t[yy][x] = Vb[(size_t)(b * 2048 + s0 + yy) * 1024 + h * 64 + d0 + x];
  __syncthreads();
  for (int yy = threadIdx.y; yy < 32; yy += 8)
    Vt[((size_t)bh * 64 + d0 + yy) * 2048 + s0 + x] = t[x][yy];
}

// ---------------------------------------------------------------------------
// QKV GEMM (unchanged): 128x128 tile, BK=64 two-subtile staging.
// ---------------------------------------------------------------------------
__global__ __launch_bounds__(256) void gemm256_qkv(
    const unsigned short* __restrict__ A,
    const unsigned short* __restrict__ Bt,
    unsigned short* __restrict__ Qo,
    unsigned short* __restrict__ Ko,
    unsigned short* __restrict__ Vo)
{
  __shared__ unsigned short sA[2][128 * 32];
  __shared__ unsigned short sB[2][128 * 32];
  const int K = 1024;
  const int m0 = blockIdx.y * 128;
  const int bn0 = blockIdx.x * 128;

  const int tid = threadIdx.x, wave = tid >> 6, lane = tid & 63;
  const int g = lane >> 4, ml = lane & 15;
  const int wm = wave & 1, wn = wave >> 1;

  const unsigned short* ag0 = A + (size_t)(m0 + (tid >> 2)) * K + (tid & 3) * 8;
  const unsigned short* ag1 = ag0 + (size_t)64 * K;
  const unsigned short* bg0 = Bt + (size_t)(bn0 + (tid >> 2)) * K + (tid & 3) * 8;
  const unsigned short* bg1 = bg0 + (size_t)64 * K;
  const int woff = wave * 512;

  floatx4 acc[4][4];
#pragma unroll
  for (int mt = 0; mt < 4; ++mt)
#pragma unroll
    for (int nt = 0; nt < 4; ++nt) acc[mt][nt] = (floatx4){0.f, 0.f, 0.f, 0.f};

  for (int k0 = 0; k0 < K; k0 += 64) {
    __syncthreads();
#pragma unroll
    for (int t = 0; t < 2; ++t) {
      gll16(ag0 + k0 + t * 32, sA[t] + woff);
      gll16(ag1 + k0 + t * 32, sA[t] + 2048 + woff);
      gll16(bg0 + k0 + t * 32, sB[t] + woff);
      gll16(bg1 + k0 + t * 32, sB[t] + 2048 + woff);
    }
    __syncthreads();
#pragma unroll
    for (int t = 0; t < 2; ++t) {
      short8 af[4], bf[4];
#pragma unroll
      for (int mt = 0; mt < 4; ++mt)
        af[mt] = *(const short8*)(sA[t] + (wm * 64 + mt * 16 + ml) * 32 + g * 8);
#pragma unroll
      for (int nt = 0; nt < 4; ++nt)
        bf[nt] = *(const short8*)(sB[t] + (wn * 64 + nt * 16 + ml) * 32 + g * 8);
#pragma unroll
      for (int mt = 0; mt < 4; ++mt)
#pragma unroll
        for (int nt = 0; nt < 4; ++nt)
          acc[mt][nt] = __builtin_amdgcn_mfma_f32_16x16x32_bf16(
              af[mt], bf[nt], acc[mt][nt], 0, 0, 0);
    }
  }

  const int proj = blockIdx.x >> 3;
  unsigned short* out = (proj == 0) ? Qo : (proj == 1) ? Ko : Vo;
  const int col0 = (blockIdx.x & 7) * 128;
#pragma unroll
  for (int mt = 0; mt < 4; ++mt) {
#pragma unroll
    for (int nt = 0; nt < 4; ++nt) {
      const int col = col0 + wn * 64 + nt * 16 + ml;
#pragma unroll
      for (int r = 0; r < 4; ++r) {
        const int row = m0 + wm * 64 + mt * 16 + g * 4 + r;
        out[(size_t)row * 1024 + col] = f2bf(acc[mt][nt][r]);
      }
    }
  }
}

// Output projection, 64x128 tile, BK=128 four-subtile staging (8 stages).
__global__ __launch_bounds__(256) void gemm_wo64(
    const unsigned short* __restrict__ A,
    const unsigned short* __restrict__ Bt,
    const float* __restrict__ bias,
    float* __restrict__ C)
{
  __shared__ unsigned short sA[4][64 * 32];
  __shared__ unsigned short sB[4][128 * 32];
  const int K = 1024;
  const int m0 = blockIdx.y * 64;
  const int bn0 = blockIdx.x * 128;
  const int tid = threadIdx.x, wave = tid >> 6, lane = tid & 63;
  const int g = lane >> 4, ml = lane & 15;
  const int wm = wave & 1, wn = wave >> 1;

  const unsigned short* ag =
      A + (size_t)(m0 + wave * 16 + (lane >> 2)) * K + (lane & 3) * 8;
  const unsigned short* bg0 = Bt + (size_t)(bn0 + (tid >> 2)) * K + (tid & 3) * 8;
  const unsigned short* bg1 = bg0 + (size_t)64 * K;
  const int woff = wave * 512;

  floatx4 acc[2][4];
#pragma unroll
  for (int mt = 0; mt < 2; ++mt)
#pragma unroll
    for (int nt = 0; nt < 4; ++nt) acc[mt][nt] = (floatx4){0.f, 0.f, 0.f, 0.f};

  for (int k0 = 0; k0 < K; k0 += 128) {
    __syncthreads();
#pragma unroll
    for (int t = 0; t < 4; ++t) {
      gll16(ag + k0 + t * 32, sA[t] + woff);
      gll16(bg0 + k0 + t * 32, sB[t] + woff);
      gll16(bg1 + k0 + t * 32, sB[t] + 2048 + woff);
    }
    __syncthreads();
#pragma unroll
    for (int t = 0; t < 4; ++t) {
      short8 af[2], bf[4];
#pragma unroll
      for (int mt = 0; mt < 2; ++mt)
        af[mt] = *(const short8*)(sA[t] + (wm * 32 + mt * 16 + ml) * 32 + g * 8);
#pragma unroll
      for (int nt = 0; nt < 4; ++nt)
        bf[nt] = *(const short8*)(sB[t] + (wn * 64 + nt * 16 + ml) * 32 + g * 8);
#pragma unroll
      for (int mt = 0; mt < 2; ++mt)
#pragma unroll
        for (int nt = 0; nt < 4; ++nt)
          acc[mt][nt] = __builtin_amdgcn_mfma_f32_16x16x32_bf16(
              af[mt], bf[nt], acc[mt][nt], 0, 0, 0);
    }
  }

#pragma unroll
  for (int mt = 0; mt < 2; ++mt) {
#pragma unroll
    for (int nt = 0; nt < 4; ++nt) {
      const int col = bn0 + wn * 64 + nt * 16 + ml;
      const float badd = bias[col];
#pragma unroll
      for (int r = 0; r < 4; ++r) {
        const int row = m0 + wm * 32 + mt * 16 + g * 4 + r;
        C[(size_t)row * 1024 + col] = acc[mt][nt][r] + badd;
      }
    }
  }
}

// ---------------------------------------------------------------------------
// Attention v12: 8-wave parity split (as v11) + in-register softmax.
// Swapped QK^T: s[nb] = mfma(K_frag, Q_frag) -> lane holds S^T, q = ml,
// k = kt*64 + nb*16 + g*4 + r. exp/mask/truncate in regs; P packed with
// v_perm (bytes 2,3 = truncated bf16), redistributed to the PV A-fragment
// layout (q=ml, k=g*8+j) with 2x permlane32_swap + 2x permlane16_swap per
// rr. l is a scalar per lane (q=ml); reduce = shfl_xor(16,32) at the end.
// LDS: K/V staging only (32KB) union epilogue comb (36KB).
// ---------------------------------------------------------------------------
constexpr int KTPB = 2;  // k-tiles per barrier

struct AttnLds {
  unsigned short k0[KTPB][64 * 32];
  unsigned short k1[KTPB][64 * 32];
  unsigned short v0[KTPB][64 * 32];
  unsigned short v1[KTPB][64 * 32];
};
union __align__(16) AttnLdsU {
  AttnLds t;
  float comb[4 * 64 * 36];  // 36 KB >= 32 KB staging; used after last barrier
};

__device__ __forceinline__ void attn_tile(
    const short8* aq,
    const unsigned short* sK0, const unsigned short* sK1,
    const unsigned short* sV0, const unsigned short* sV1,
    floatx4* acc, float& l,
    const bool diag, const int qg /* qrow0+ml */, const int kb /* kcol0+g*4 */,
    const int g, const int ml)
{
  const float C1 = 0.18033688f;    // 0.125 / ln2
  const float C2 = -34.6246810f;   // -24 / ln2

  floatx4 s[4];
#pragma unroll
  for (int nb = 0; nb < 4; ++nb) {
    s[nb] = (floatx4){0.f, 0.f, 0.f, 0.f};
    short8 bk0 = *(const short8*)(sK0 + (nb * 16 + ml) * 32 + g * 8);
    s[nb] = __builtin_amdgcn_mfma_f32_16x16x32_bf16(bk0, aq[0], s[nb], 0, 0, 0);
    short8 bk1 = *(const short8*)(sK1 + (nb * 16 + ml) * 32 + g * 8);
    s[nb] = __builtin_amdgcn_mfma_f32_16x16x32_bf16(bk1, aq[1], s[nb], 0, 0, 0);
  }

  // exp + causal mask + truncate-to-bf16 (bits) + rowsum of truncated vals.
  unsigned wb[4][4];
#pragma unroll
  for (int nb = 0; nb < 4; ++nb) {
#pragma unroll
    for (int r = 0; r < 4; ++r) {
      float wv = fast_exp2(fmaf(s[nb][r], C1, C2));
      if (diag && (kb + nb * 16 + r > qg)) wv = 0.f;
      const unsigned bits = __float_as_uint(wv) & 0xffff0000u;
      wb[nb][r] = bits;
      l += __uint_as_float(bits);
    }
  }

  // pack pairs along r: pk[nb][rr] = {lo = w[nb][2rr], hi = w[nb][2rr+1]}
  // (v_perm bytes 2,3 of each source = truncated bf16)
  unsigned pk[4][2];
#pragma unroll
  for (int nb = 0; nb < 4; ++nb) {
    pk[nb][0] = __builtin_amdgcn_perm(wb[nb][1], wb[nb][0], 0x07060302u);
    pk[nb][1] = __builtin_amdgcn_perm(wb[nb][3], wb[nb][2], 0x07060302u);
  }

  // redistribute to PV A-frag: value pk[2n1+n0][rr] @ lane(L1,L0) must land
  // in F[n1] dword (2*L0+rr) @ lane(n0,L1).  Bit map (reg0,lane5,lane4):
  // swap reg0<->lane5 (permlane32_swap on reg pairs), then reg0<->lane4
  // (permlane16_swap).
  unsigned Fr[2][4];
#pragma unroll
  for (int rr = 0; rr < 2; ++rr) {
    unsigned a0 = pk[0][rr], a1 = pk[1][rr];
    unsigned a2 = pk[2][rr], a3 = pk[3][rr];
    asm("v_permlane32_swap_b32 %0, %1" : "+v"(a0), "+v"(a1));
    asm("v_permlane32_swap_b32 %0, %1" : "+v"(a2), "+v"(a3));
    asm("v_permlane16_swap_b32 %0, %1" : "+v"(a0), "+v"(a1));
    asm("v_permlane16_swap_b32 %0, %1" : "+v"(a2), "+v"(a3));
    Fr[0][rr] = a0; Fr[0][2 + rr] = a1;
    Fr[1][rr] = a2; Fr[1][2 + rr] = a3;
  }

#pragma unroll
  for (int f = 0; f < 2; ++f) {
    union { unsigned u[4]; short8 s8; } uap;
    uap.u[0] = Fr[f][0]; uap.u[1] = Fr[f][1];
    uap.u[2] = Fr[f][2]; uap.u[3] = Fr[f][3];
    const short8 ap = uap.s8;
    const unsigned short* sv = f ? sV1 : sV0;
#pragma unroll
    for (int jd = 0; jd < 4; ++jd) {
      short8 bv = *(const short8*)(sv + (jd * 16 + ml) * 32 + g * 8);
      acc[jd] = __builtin_amdgcn_mfma_f32_16x16x32_bf16(ap, bv, acc[jd], 0, 0, 0);
    }
  }
}

__global__ __launch_bounds__(512) void attn_v12(
    const unsigned short* __restrict__ Q,
    const unsigned short* __restrict__ Kg,
    const unsigned short* __restrict__ Vt,
    unsigned short* __restrict__ CTX)
{
  __shared__ AttnLdsU lds;

  const int bh = blockIdx.y;
  const int b = bh >> 4, h = bh & 15;
  const int p = blockIdx.x;
  const int qbA = p, qbB = 31 - p;
  const int qA0 = qbA * 64, qB0 = qbB * 64;
  const int tid = threadIdx.x, w = tid >> 6, lane = tid & 63;
  const int slice = w & 3, par = w >> 2;
  const int g = lane >> 4, ml = lane & 15;

  const size_t headoff = (size_t)b * S_ * D_ + (size_t)h * HD_;
  const size_t vtoff   = (size_t)bh * HD_ * S_;

  short8 aqA[2], aqB[2];
  {
    const unsigned short* qp =
        Q + headoff + (size_t)(qA0 + slice * 16 + ml) * D_ + g * 8;
    aqA[0] = *(const short8*)qp;
    aqA[1] = *(const short8*)(qp + 32);
  }
  {
    const unsigned short* qp =
        Q + headoff + (size_t)(qB0 + slice * 16 + ml) * D_ + g * 8;
    aqB[0] = *(const short8*)qp;
    aqB[1] = *(const short8*)(qp + 32);
  }

  floatx4 accA[4], accB[4];
#pragma unroll
  for (int jd = 0; jd < 4; ++jd) {
    accA[jd] = (floatx4){0.f, 0.f, 0.f, 0.f};
    accB[jd] = (floatx4){0.f, 0.f, 0.f, 0.f};
  }
  float lA = 0.f, lB = 0.f;
  const int qgA = qA0 + slice * 16 + ml;   // this lane's q-row (A block)
  const int qgB = qB0 + slice * 16 + ml;

  // staging: waves 0-3 handle K, waves 4-7 handle V; each covers 16 rows.
  const int sw = slice;
  const unsigned short* kgb =
      Kg + headoff + (size_t)(sw * 16 + (lane >> 2)) * D_ + (lane & 3) * 8;
  const unsigned short* vgb =
      Vt + vtoff + (size_t)(sw * 16 + (lane >> 2)) * S_ + (lane & 3) * 8;
  const int woff = sw * 512;

  const int ntiles = qbB + 1;
  for (int kt0 = 0; kt0 < ntiles; kt0 += KTPB) {
    const int cnt = (ntiles - kt0 < KTPB) ? (ntiles - kt0) : KTPB;  // uniform
    __syncthreads();
#pragma unroll
    for (int t = 0; t < KTPB; ++t) {
      if (t >= cnt) break;
      const int kt = kt0 + t;
      if (w < 4) {
        const size_t ko = (size_t)kt * 64 * D_;
        gll16(kgb + ko,      lds.t.k0[t] + woff);
        gll16(kgb + ko + 32, lds.t.k1[t] + woff);
      } else {
        gll16(vgb + kt * 64,      lds.t.v0[t] + woff);
        gll16(vgb + kt * 64 + 32, lds.t.v1[t] + woff);
      }
    }
    __syncthreads();

    if (par < cnt) {
      const int kt = kt0 + par;
      const int kb = kt * 64 + g * 4;
      attn_tile(aqB, lds.t.k0[par], lds.t.k1[par], lds.t.v0[par], lds.t.v1[par],
                accB, lB, kt == qbB, qgB, kb, g, ml);
      if (kt <= qbA)
        attn_tile(aqA, lds.t.k0[par], lds.t.k1[par], lds.t.v0[par], lds.t.v1[par],
                  accA, lA, kt == qbA, qgA, kb, g, ml);
    }
  }

  // ---- combine parity pairs (w, w+4) through LDS ----
  __syncthreads();
  {
    float* slot = lds.comb + (size_t)(slice * 64 + lane) * 36;
    if (par == 1) {
#pragma unroll
      for (int jd = 0; jd < 4; ++jd) {
        *(floatx4*)(slot + jd * 4) = accA[jd];
        *(floatx4*)(slot + 16 + jd * 4) = accB[jd];
      }
      slot[32] = lA;
      slot[33] = lB;
    }
    __syncthreads();
    if (par == 1) return;  // upper waves done; no further barriers below
#pragma unroll
    for (int jd = 0; jd < 4; ++jd) {
      accA[jd] += *(const floatx4*)(slot + jd * 4);
      accB[jd] += *(const floatx4*)(slot + 16 + jd * 4);
    }
    lA += slot[32];
    lB += slot[33];
  }

  // reduce l across the 4 lanes sharing ml (k was spread over g), invert,
  // then fetch per-output-row values (row = g*4+r lives at lane ml=g*4+r).
  lA += __shfl_xor(lA, 16); lA += __shfl_xor(lA, 32);
  lB += __shfl_xor(lB, 16); lB += __shfl_xor(lB, 32);
  const float liA = 1.0f / lA;
  const float liB = 1.0f / lB;
  float lrA[4], lrB[4];
#pragma unroll
  for (int r = 0; r < 4; ++r) {
    lrA[r] = __shfl(liA, g * 4 + r);
    lrB[r] = __shfl(liB, g * 4 + r);
  }

#pragma unroll
  for (int r = 0; r < 4; ++r) {
    const int rowA = qA0 + slice * 16 + g * 4 + r;
    const int rowB = qB0 + slice * 16 + g * 4 + r;
#pragma unroll
    for (int jd = 0; jd < 4; ++jd) {
      CTX[headoff + (size_t)rowA * D_ + jd * 16 + ml] = f2bf(accA[jd][r] * lrA[r]);
      CTX[headoff + (size_t)rowB * D_ + jd * 16 + ml] = f2bf(accB[jd][r] * lrB[r]);
    }
  }
}

// ---------------------------------------------------------------------------
extern "C" void kernel_launch(void* const* d_in, const int* in_sizes, int n_in,
                              void* d_out, int out_size, void* d_ws, size_t ws_size,
                              hipStream_t stream)
{
  const float* X  = (const float*)d_in[0];
  const float* Wq = (const float*)d_in[1];
  const float* Wk = (const float*)d_in[2];
  const float* Wv = (const float*)d_in[3];
  const float* Wo = (const float*)d_in[4];
  const float* bo = (const float*)d_in[5];

  char* ws = (char*)d_ws;
  const size_t MB = 1024 * 1024;

  unsigned short* Qb  = (unsigned short*)(ws);            // 8 MB (CTX aliases)
  unsigned short* Kb  = (unsigned short*)(ws + 8 * MB);   // 8 MB
  unsigned short* Xb  = (unsigned short*)(ws + 16 * MB);  // 8 MB; Vt after QKV
  unsigned short* WT  = (unsigned short*)(ws + 24 * MB);  // WqT|WkT|WvT|WoT
  unsigned short* WoT = WT + (size_t)3 * 1024 * 1024;
  unsigned short* Vb  = (unsigned short*)d_out;           // low 8MB of d_out
  unsigned short* Vt  = Xb;                               // reuse dead Xb

  // merged X-convert (z=4) + 4x W transpose/convert (z=0..3)
  prep_inputs<<<dim3(32, 32, 5), dim3(32, 8), 0, stream>>>(
      X, Xb, Wq, Wk, Wv, Wo, WT);
  // fused Q/K/V projection: Bt = WT[0..3071][1024], BK=64 staging
  gemm256_qkv<<<dim3(24, 32), 256, 0, stream>>>(Xb, WT, Qb, Kb, Vb);
  // V -> Vt[(b*16+h)*64+d][s]  (Xb dead now)
  transpose_v<<<dim3(64, 2, 32), dim3(32, 8), 0, stream>>>(Vb, Vt);
  // 8-wave parity-split attention, in-register softmax; CTX aliases Q
  attn_v12<<<dim3(16, B_ * H_), 512, 0, stream>>>(Qb, Kb, Vt, Qb);
  // output projection + bias (64x128 tile, BK=128, 512 blocks)
  gemm_wo64<<<dim3(8, 64), 256, 0, stream>>>(Qb, WoT, bo, (float*)d_out);
}

// Round 3
// 187.815 us; speedup vs baseline: 1.0944x; 1.0707x over previous
//
#include <hip/hip_runtime.h>

// MultiHeadAttention: B=2, S=2048, D=1024, H=16, hd=64. fp32 I/O.
// Round 19: attention fetch-latency fixes.
// (1) 2-phase pipeline (T3 minimum): stage NEXT 2-tile group into buf^1,
//     compute current buf, ONE barrier per iteration. The vmcnt(0) drain
//     at the barrier covers loads issued a compute-phase earlier -> HBM/L2
//     latency hidden. K/V LDS double-buffered (64KB, still 2 blocks/CU).
// (2) XCD-chunked block swizzle (T1): rid=(L&7)*64+(L>>3) groups all 16
//     p-blocks of 4 consecutive bh per XCD -> K/V working set 2MB < 4MB L2
//     -> K/V fetched from HBM once (was ~4x, 62.5MB).
// In-register softmax (R18) kept. GEMMs unchanged.

typedef __attribute__((ext_vector_type(8))) short short8;
typedef __attribute__((ext_vector_type(4))) float floatx4;

__device__ inline unsigned short f2bf(float f) {
  unsigned u = __float_as_uint(f);
  unsigned r = (u + 0x7fffu + ((u >> 16) & 1u)) >> 16;  // RNE
  return (unsigned short)r;
}

__device__ __forceinline__ float fast_exp2(float x) {
#if __has_builtin(__builtin_amdgcn_exp2f)
  return __builtin_amdgcn_exp2f(x);
#else
  float r;
  asm volatile("v_exp_f32_e32 %0, %1" : "=v"(r) : "v"(x));
  return r;
#endif
}

__device__ __forceinline__ void gll16(const unsigned short* g, unsigned short* l) {
  __builtin_amdgcn_global_load_lds(
      (const __attribute__((address_space(1))) unsigned int*)(g),
      (__attribute__((address_space(3))) unsigned int*)(l),
      16, 0, 0);
}

constexpr int B_ = 2, S_ = 2048, D_ = 1024, H_ = 16, HD_ = 64;

// ---------------------------------------------------------------------------
// Merged one-time converter: z=0..3 -> W transpose+convert; z=4 -> X convert.
// ---------------------------------------------------------------------------
__global__ __launch_bounds__(256) void prep_inputs(
    const float* __restrict__ x, unsigned short* __restrict__ xb,
    const float* __restrict__ w0, const float* __restrict__ w1,
    const float* __restrict__ w2, const float* __restrict__ w3,
    unsigned short* __restrict__ wt_base)
{
  if (blockIdx.z == 4) {
    const int tid = threadIdx.y * 32 + threadIdx.x;
    const size_t base =
        ((size_t)(blockIdx.y * 32 + blockIdx.x) * 256 + tid) * 16;
#pragma unroll
    for (int half = 0; half < 2; ++half) {
      const size_t i = base + half * 8;
      float4 a = *(const float4*)(x + i);
      float4 b = *(const float4*)(x + i + 4);
      short8 o;
      o[0] = (short)f2bf(a.x); o[1] = (short)f2bf(a.y);
      o[2] = (short)f2bf(a.z); o[3] = (short)f2bf(a.w);
      o[4] = (short)f2bf(b.x); o[5] = (short)f2bf(b.y);
      o[6] = (short)f2bf(b.z); o[7] = (short)f2bf(b.w);
      *(short8*)(xb + i) = o;
    }
    return;
  }
  const float* src;
  switch (blockIdx.z) {
    case 0: src = w0; break;
    case 1: src = w1; break;
    case 2: src = w2; break;
    default: src = w3; break;
  }
  unsigned short* dst = wt_base + (size_t)blockIdx.z * 1024 * 1024;
  __shared__ unsigned short t[32][33];
  const int bx = blockIdx.x * 32;  // n
  const int by = blockIdx.y * 32;  // k
  const int x_ = threadIdx.x;
  for (int yy = threadIdx.y; yy < 32; yy += 8)
    t[yy][x_] = f2bf(src[(size_t)(by + yy) * 1024 + bx + x_]);
  __syncthreads();
  for (int yy = threadIdx.y; yy < 32; yy += 8)
    dst[(size_t)(bx + yy) * 1024 + by + x_] = t[x_][yy];
}

// Vb[b][s][h*64+d] bf16 -> Vt[(b*16+h)*64+d][s] bf16
__global__ __launch_bounds__(256) void transpose_v(
    const unsigned short* __restrict__ Vb, unsigned short* __restrict__ Vt)
{
  __shared__ unsigned short t[32][33];
  const int bh = blockIdx.z;
  const int b = bh >> 4, h = bh & 15;
  const int s0 = blockIdx.x * 32, d0 = blockIdx.y * 32;
  const int x = threadIdx.x;
  for (int yy = threadIdx.y; yy < 32; yy += 8)
    t[yy][x] = Vb[(size_t)(b * 2048 + s0 + yy) * 1024 + h * 64 + d0 + x];
  __syncthreads();
  for (int yy = threadIdx.y; yy < 32; yy += 8)
    Vt[((size_t)bh * 64 + d0 + yy) * 2048 + s0 + x] = t[x][yy];
}

// ---------------------------------------------------------------------------
// QKV GEMM (unchanged): 128x128 tile, BK=64 two-subtile staging.
// ---------------------------------------------------------------------------
__global__ __launch_bounds__(256) void gemm256_qkv(
    const unsigned short* __restrict__ A,
    const unsigned short* __restrict__ Bt,
    unsigned short* __restrict__ Qo,
    unsigned short* __restrict__ Ko,
    unsigned short* __restrict__ Vo)
{
  __shared__ unsigned short sA[2][128 * 32];
  __shared__ unsigned short sB[2][128 * 32];
  const int K = 1024;
  const int m0 = blockIdx.y * 128;
  const int bn0 = blockIdx.x * 128;

  const int tid = threadIdx.x, wave = tid >> 6, lane = tid & 63;
  const int g = lane >> 4, ml = lane & 15;
  const int wm = wave & 1, wn = wave >> 1;

  const unsigned short* ag0 = A + (size_t)(m0 + (tid >> 2)) * K + (tid & 3) * 8;
  const unsigned short* ag1 = ag0 + (size_t)64 * K;
  const unsigned short* bg0 = Bt + (size_t)(bn0 + (tid >> 2)) * K + (tid & 3) * 8;
  const unsigned short* bg1 = bg0 + (size_t)64 * K;
  const int woff = wave * 512;

  floatx4 acc[4][4];
#pragma unroll
  for (int mt = 0; mt < 4; ++mt)
#pragma unroll
    for (int nt = 0; nt < 4; ++nt) acc[mt][nt] = (floatx4){0.f, 0.f, 0.f, 0.f};

  for (int k0 = 0; k0 < K; k0 += 64) {
    __syncthreads();
#pragma unroll
    for (int t = 0; t < 2; ++t) {
      gll16(ag0 + k0 + t * 32, sA[t] + woff);
      gll16(ag1 + k0 + t * 32, sA[t] + 2048 + woff);
      gll16(bg0 + k0 + t * 32, sB[t] + woff);
      gll16(bg1 + k0 + t * 32, sB[t] + 2048 + woff);
    }
    __syncthreads();
#pragma unroll
    for (int t = 0; t < 2; ++t) {
      short8 af[4], bf[4];
#pragma unroll
      for (int mt = 0; mt < 4; ++mt)
        af[mt] = *(const short8*)(sA[t] + (wm * 64 + mt * 16 + ml) * 32 + g * 8);
#pragma unroll
      for (int nt = 0; nt < 4; ++nt)
        bf[nt] = *(const short8*)(sB[t] + (wn * 64 + nt * 16 + ml) * 32 + g * 8);
#pragma unroll
      for (int mt = 0; mt < 4; ++mt)
#pragma unroll
        for (int nt = 0; nt < 4; ++nt)
          acc[mt][nt] = __builtin_amdgcn_mfma_f32_16x16x32_bf16(
              af[mt], bf[nt], acc[mt][nt], 0, 0, 0);
    }
  }

  const int proj = blockIdx.x >> 3;
  unsigned short* out = (proj == 0) ? Qo : (proj == 1) ? Ko : Vo;
  const int col0 = (blockIdx.x & 7) * 128;
#pragma unroll
  for (int mt = 0; mt < 4; ++mt) {
#pragma unroll
    for (int nt = 0; nt < 4; ++nt) {
      const int col = col0 + wn * 64 + nt * 16 + ml;
#pragma unroll
      for (int r = 0; r < 4; ++r) {
        const int row = m0 + wm * 64 + mt * 16 + g * 4 + r;
        out[(size_t)row * 1024 + col] = f2bf(acc[mt][nt][r]);
      }
    }
  }
}

// Output projection, 64x128 tile, BK=128 four-subtile staging (8 stages).
__global__ __launch_bounds__(256) void gemm_wo64(
    const unsigned short* __restrict__ A,
    const unsigned short* __restrict__ Bt,
    const float* __restrict__ bias,
    float* __restrict__ C)
{
  __shared__ unsigned short sA[4][64 * 32];
  __shared__ unsigned short sB[4][128 * 32];
  const int K = 1024;
  const int m0 = blockIdx.y * 64;
  const int bn0 = blockIdx.x * 128;
  const int tid = threadIdx.x, wave = tid >> 6, lane = tid & 63;
  const int g = lane >> 4, ml = lane & 15;
  const int wm = wave & 1, wn = wave >> 1;

  const unsigned short* ag =
      A + (size_t)(m0 + wave * 16 + (lane >> 2)) * K + (lane & 3) * 8;
  const unsigned short* bg0 = Bt + (size_t)(bn0 + (tid >> 2)) * K + (tid & 3) * 8;
  const unsigned short* bg1 = bg0 + (size_t)64 * K;
  const int woff = wave * 512;

  floatx4 acc[2][4];
#pragma unroll
  for (int mt = 0; mt < 2; ++mt)
#pragma unroll
    for (int nt = 0; nt < 4; ++nt) acc[mt][nt] = (floatx4){0.f, 0.f, 0.f, 0.f};

  for (int k0 = 0; k0 < K; k0 += 128) {
    __syncthreads();
#pragma unroll
    for (int t = 0; t < 4; ++t) {
      gll16(ag + k0 + t * 32, sA[t] + woff);
      gll16(bg0 + k0 + t * 32, sB[t] + woff);
      gll16(bg1 + k0 + t * 32, sB[t] + 2048 + woff);
    }
    __syncthreads();
#pragma unroll
    for (int t = 0; t < 4; ++t) {
      short8 af[2], bf[4];
#pragma unroll
      for (int mt = 0; mt < 2; ++mt)
        af[mt] = *(const short8*)(sA[t] + (wm * 32 + mt * 16 + ml) * 32 + g * 8);
#pragma unroll
      for (int nt = 0; nt < 4; ++nt)
        bf[nt] = *(const short8*)(sB[t] + (wn * 64 + nt * 16 + ml) * 32 + g * 8);
#pragma unroll
      for (int mt = 0; mt < 2; ++mt)
#pragma unroll
        for (int nt = 0; nt < 4; ++nt)
          acc[mt][nt] = __builtin_amdgcn_mfma_f32_16x16x32_bf16(
              af[mt], bf[nt], acc[mt][nt], 0, 0, 0);
    }
  }

#pragma unroll
  for (int mt = 0; mt < 2; ++mt) {
#pragma unroll
    for (int nt = 0; nt < 4; ++nt) {
      const int col = bn0 + wn * 64 + nt * 16 + ml;
      const float badd = bias[col];
#pragma unroll
      for (int r = 0; r < 4; ++r) {
        const int row = m0 + wm * 32 + mt * 16 + g * 4 + r;
        C[(size_t)row * 1024 + col] = acc[mt][nt][r] + badd;
      }
    }
  }
}

// ---------------------------------------------------------------------------
// Attention v13: 8-wave parity split + in-register softmax (v12) +
// double-buffered 2-phase staging + XCD-chunked block swizzle.
// LDS: 2 bufs x 2 tiles x (K 8KB + V 8KB) = 64KB; union comb 36KB.
// ---------------------------------------------------------------------------
constexpr int KTPB = 2;  // k-tiles per buffer group

struct AttnLds {
  unsigned short k0[2][KTPB][64 * 32];
  unsigned short k1[2][KTPB][64 * 32];
  unsigned short v0[2][KTPB][64 * 32];
  unsigned short v1[2][KTPB][64 * 32];
};
union __align__(16) AttnLdsU {
  AttnLds t;
  float comb[4 * 64 * 36];  // 36 KB <= 64 KB; used after last barrier
};

__device__ __forceinline__ void attn_tile(
    const short8* aq,
    const unsigned short* sK0, const unsigned short* sK1,
    const unsigned short* sV0, const unsigned short* sV1,
    floatx4* acc, float& l,
    const bool diag, const int qg /* qrow0+ml */, const int kb /* kcol0+g*4 */,
    const int g, const int ml)
{
  const float C1 = 0.18033688f;    // 0.125 / ln2
  const float C2 = -34.6246810f;   // -24 / ln2

  floatx4 s[4];
#pragma unroll
  for (int nb = 0; nb < 4; ++nb) {
    s[nb] = (floatx4){0.f, 0.f, 0.f, 0.f};
    short8 bk0 = *(const short8*)(sK0 + (nb * 16 + ml) * 32 + g * 8);
    s[nb] = __builtin_amdgcn_mfma_f32_16x16x32_bf16(bk0, aq[0], s[nb], 0, 0, 0);
    short8 bk1 = *(const short8*)(sK1 + (nb * 16 + ml) * 32 + g * 8);
    s[nb] = __builtin_amdgcn_mfma_f32_16x16x32_bf16(bk1, aq[1], s[nb], 0, 0, 0);
  }

  // exp + causal mask + truncate-to-bf16 (bits) + rowsum of truncated vals.
  unsigned wb[4][4];
#pragma unroll
  for (int nb = 0; nb < 4; ++nb) {
#pragma unroll
    for (int r = 0; r < 4; ++r) {
      float wv = fast_exp2(fmaf(s[nb][r], C1, C2));
      if (diag && (kb + nb * 16 + r > qg)) wv = 0.f;
      const unsigned bits = __float_as_uint(wv) & 0xffff0000u;
      wb[nb][r] = bits;
      l += __uint_as_float(bits);
    }
  }

  // pack pairs along r (v_perm bytes 2,3 of each source = truncated bf16)
  unsigned pk[4][2];
#pragma unroll
  for (int nb = 0; nb < 4; ++nb) {
    pk[nb][0] = __builtin_amdgcn_perm(wb[nb][1], wb[nb][0], 0x07060302u);
    pk[nb][1] = __builtin_amdgcn_perm(wb[nb][3], wb[nb][2], 0x07060302u);
  }

  // redistribute to PV A-frag: 2x permlane32_swap + 2x permlane16_swap per rr
  unsigned Fr[2][4];
#pragma unroll
  for (int rr = 0; rr < 2; ++rr) {
    unsigned a0 = pk[0][rr], a1 = pk[1][rr];
    unsigned a2 = pk[2][rr], a3 = pk[3][rr];
    asm("v_permlane32_swap_b32 %0, %1" : "+v"(a0), "+v"(a1));
    asm("v_permlane32_swap_b32 %0, %1" : "+v"(a2), "+v"(a3));
    asm("v_permlane16_swap_b32 %0, %1" : "+v"(a0), "+v"(a1));
    asm("v_permlane16_swap_b32 %0, %1" : "+v"(a2), "+v"(a3));
    Fr[0][rr] = a0; Fr[0][2 + rr] = a1;
    Fr[1][rr] = a2; Fr[1][2 + rr] = a3;
  }

#pragma unroll
  for (int f = 0; f < 2; ++f) {
    union { unsigned u[4]; short8 s8; } uap;
    uap.u[0] = Fr[f][0]; uap.u[1] = Fr[f][1];
    uap.u[2] = Fr[f][2]; uap.u[3] = Fr[f][3];
    const short8 ap = uap.s8;
    const unsigned short* sv = f ? sV1 : sV0;
#pragma unroll
    for (int jd = 0; jd < 4; ++jd) {
      short8 bv = *(const short8*)(sv + (jd * 16 + ml) * 32 + g * 8);
      acc[jd] = __builtin_amdgcn_mfma_f32_16x16x32_bf16(ap, bv, acc[jd], 0, 0, 0);
    }
  }
}

__global__ __launch_bounds__(512) void attn_v13(
    const unsigned short* __restrict__ Q,
    const unsigned short* __restrict__ Kg,
    const unsigned short* __restrict__ Vt,
    unsigned short* __restrict__ CTX)
{
  __shared__ AttnLdsU lds;

  // XCD-chunked swizzle: hardware round-robins linear id % 8 across XCDs.
  // rid groups all 16 p-blocks of 4 consecutive bh onto one XCD -> K/V
  // working set 4*512KB/4 = 2MB per XCD L2. 512 % 8 == 0 -> bijective.
  const int L = blockIdx.x;
  const int rid = (L & 7) * 64 + (L >> 3);
  const int p = rid & 15;
  const int bh = rid >> 4;

  const int b = bh >> 4, h = bh & 15;
  const int qbA = p, qbB = 31 - p;
  const int qA0 = qbA * 64, qB0 = qbB * 64;
  const int tid = threadIdx.x, w = tid >> 6, lane = tid & 63;
  const int slice = w & 3, par = w >> 2;
  const int g = lane >> 4, ml = lane & 15;

  const size_t headoff = (size_t)b * S_ * D_ + (size_t)h * HD_;
  const size_t vtoff   = (size_t)bh * HD_ * S_;

  short8 aqA[2], aqB[2];
  {
    const unsigned short* qp =
        Q + headoff + (size_t)(qA0 + slice * 16 + ml) * D_ + g * 8;
    aqA[0] = *(const short8*)qp;
    aqA[1] = *(const short8*)(qp + 32);
  }
  {
    const unsigned short* qp =
        Q + headoff + (size_t)(qB0 + slice * 16 + ml) * D_ + g * 8;
    aqB[0] = *(const short8*)qp;
    aqB[1] = *(const short8*)(qp + 32);
  }

  floatx4 accA[4], accB[4];
#pragma unroll
  for (int jd = 0; jd < 4; ++jd) {
    accA[jd] = (floatx4){0.f, 0.f, 0.f, 0.f};
    accB[jd] = (floatx4){0.f, 0.f, 0.f, 0.f};
  }
  float lA = 0.f, lB = 0.f;
  const int qgA = qA0 + slice * 16 + ml;   // this lane's q-row (A block)
  const int qgB = qB0 + slice * 16 + ml;

  // staging: waves 0-3 handle K, waves 4-7 handle V; each covers 16 rows.
  const int sw = slice;
  const unsigned short* kgb =
      Kg + headoff + (size_t)(sw * 16 + (lane >> 2)) * D_ + (lane & 3) * 8;
  const unsigned short* vgb =
      Vt + vtoff + (size_t)(sw * 16 + (lane >> 2)) * S_ + (lane & 3) * 8;
  const int woff = sw * 512;

  const int ntiles = qbB + 1;

  // ---- stage group 0 into buf 0 (prologue; one unhidden drain) ----
  {
    const int cnt = (ntiles < KTPB) ? ntiles : KTPB;
#pragma unroll
    for (int t = 0; t < KTPB; ++t) {
      if (t >= cnt) break;
      if (w < 4) {
        const size_t ko = (size_t)t * 64 * D_;
        gll16(kgb + ko,      lds.t.k0[0][t] + woff);
        gll16(kgb + ko + 32, lds.t.k1[0][t] + woff);
      } else {
        gll16(vgb + t * 64,      lds.t.v0[0][t] + woff);
        gll16(vgb + t * 64 + 32, lds.t.v1[0][t] + woff);
      }
    }
  }
  __syncthreads();

  for (int kt0 = 0; kt0 < ntiles; kt0 += KTPB) {
    const int bufi = (kt0 >> 1) & 1;
    // ---- stage NEXT group into buf^1 (issue early; drained at barrier) ----
    const int nxt = kt0 + KTPB;
    if (nxt < ntiles) {
      const int cn = (ntiles - nxt < KTPB) ? (ntiles - nxt) : KTPB;
#pragma unroll
      for (int t = 0; t < KTPB; ++t) {
        if (t >= cn) break;
        const int kt = nxt + t;
        if (w < 4) {
          const size_t ko = (size_t)kt * 64 * D_;
          gll16(kgb + ko,      lds.t.k0[bufi ^ 1][t] + woff);
          gll16(kgb + ko + 32, lds.t.k1[bufi ^ 1][t] + woff);
        } else {
          gll16(vgb + kt * 64,      lds.t.v0[bufi ^ 1][t] + woff);
          gll16(vgb + kt * 64 + 32, lds.t.v1[bufi ^ 1][t] + woff);
        }
      }
    }

    // ---- compute current buf ----
    const int cnt = (ntiles - kt0 < KTPB) ? (ntiles - kt0) : KTPB;  // uniform
    if (par < cnt) {
      const int kt = kt0 + par;
      const int kb = kt * 64 + g * 4;
      attn_tile(aqB, lds.t.k0[bufi][par], lds.t.k1[bufi][par],
                lds.t.v0[bufi][par], lds.t.v1[bufi][par],
                accB, lB, kt == qbB, qgB, kb, g, ml);
      if (kt <= qbA)
        attn_tile(aqA, lds.t.k0[bufi][par], lds.t.k1[bufi][par],
                  lds.t.v0[bufi][par], lds.t.v1[bufi][par],
                  accA, lA, kt == qbA, qgA, kb, g, ml);
    }
    __syncthreads();  // drains next-group loads (hidden under compute)
  }

  // ---- combine parity pairs (w, w+4) through LDS ----
  {
    float* slot = lds.comb + (size_t)(slice * 64 + lane) * 36;
    if (par == 1) {
#pragma unroll
      for (int jd = 0; jd < 4; ++jd) {
        *(floatx4*)(slot + jd * 4) = accA[jd];
        *(floatx4*)(slot + 16 + jd * 4) = accB[jd];
      }
      slot[32] = lA;
      slot[33] = lB;
    }
    __syncthreads();
    if (par == 1) return;  // upper waves done; no further barriers below
#pragma unroll
    for (int jd = 0; jd < 4; ++jd) {
      accA[jd] += *(const floatx4*)(slot + jd * 4);
      accB[jd] += *(const floatx4*)(slot + 16 + jd * 4);
    }
    lA += slot[32];
    lB += slot[33];
  }

  // reduce l across the 4 lanes sharing ml (k was spread over g), invert,
  // then fetch per-output-row values (row = g*4+r lives at lane ml=g*4+r).
  lA += __shfl_xor(lA, 16); lA += __shfl_xor(lA, 32);
  lB += __shfl_xor(lB, 16); lB += __shfl_xor(lB, 32);
  const float liA = 1.0f / lA;
  const float liB = 1.0f / lB;
  float lrA[4], lrB[4];
#pragma unroll
  for (int r = 0; r < 4; ++r) {
    lrA[r] = __shfl(liA, g * 4 + r);
    lrB[r] = __shfl(liB, g * 4 + r);
  }

#pragma unroll
  for (int r = 0; r < 4; ++r) {
    const int rowA = qA0 + slice * 16 + g * 4 + r;
    const int rowB = qB0 + slice * 16 + g * 4 + r;
#pragma unroll
    for (int jd = 0; jd < 4; ++jd) {
      CTX[headoff + (size_t)rowA * D_ + jd * 16 + ml] = f2bf(accA[jd][r] * lrA[r]);
      CTX[headoff + (size_t)rowB * D_ + jd * 16 + ml] = f2bf(accB[jd][r] * lrB[r]);
    }
  }
}

// ---------------------------------------------------------------------------
extern "C" void kernel_launch(void* const* d_in, const int* in_sizes, int n_in,
                              void* d_out, int out_size, void* d_ws, size_t ws_size,
                              hipStream_t stream)
{
  const float* X  = (const float*)d_in[0];
  const float* Wq = (const float*)d_in[1];
  const float* Wk = (const float*)d_in[2];
  const float* Wv = (const float*)d_in[3];
  const float* Wo = (const float*)d_in[4];
  const float* bo = (const float*)d_in[5];

  char* ws = (char*)d_ws;
  const size_t MB = 1024 * 1024;

  unsigned short* Qb  = (unsigned short*)(ws);            // 8 MB (CTX aliases)
  unsigned short* Kb  = (unsigned short*)(ws + 8 * MB);   // 8 MB
  unsigned short* Xb  = (unsigned short*)(ws + 16 * MB);  // 8 MB; Vt after QKV
  unsigned short* WT  = (unsigned short*)(ws + 24 * MB);  // WqT|WkT|WvT|WoT
  unsigned short* WoT = WT + (size_t)3 * 1024 * 1024;
  unsigned short* Vb  = (unsigned short*)d_out;           // low 8MB of d_out
  unsigned short* Vt  = Xb;                               // reuse dead Xb

  // merged X-convert (z=4) + 4x W transpose/convert (z=0..3)
  prep_inputs<<<dim3(32, 32, 5), dim3(32, 8), 0, stream>>>(
      X, Xb, Wq, Wk, Wv, Wo, WT);
  // fused Q/K/V projection: Bt = WT[0..3071][1024], BK=64 staging
  gemm256_qkv<<<dim3(24, 32), 256, 0, stream>>>(Xb, WT, Qb, Kb, Vb);
  // V -> Vt[(b*16+h)*64+d][s]  (Xb dead now)
  transpose_v<<<dim3(64, 2, 32), dim3(32, 8), 0, stream>>>(Vb, Vt);
  // 2-phase pipelined, XCD-swizzled attention; CTX aliases Q
  attn_v13<<<dim3(512), 512, 0, stream>>>(Qb, Kb, Vt, Qb);
  // output projection + bias (64x128 tile, BK=128, 512 blocks)
  gemm_wo64<<<dim3(8, 64), 256, 0, stream>>>(Qb, WoT, bo, (float*)d_out);
}

// Round 5
// 185.094 us; speedup vs baseline: 1.1105x; 1.0147x over previous
//
#include <hip/hip_runtime.h>

// MultiHeadAttention: B=2, S=2048, D=1024, H=16, hd=64. fp32 I/O.
// Round 21: BISECTION of R20's failure. R20 bundled {LDS swizzle, A/B
// fusion, launch_bounds(512,4)} and failed correctness (absmax 0.13,
// run-to-run variance). This round keeps ONLY the A/B fusion (provably
// bit-identical to the passing v13: same ops, same order, only register
// reuse of K/V fragments) and reverts swizzle + bounds to v13's exact
// passing configuration. If this passes, R22 re-attacks bank conflicts.
// v13 base: 2-phase pipeline + XCD-chunked swizzle + in-register softmax.

typedef __attribute__((ext_vector_type(8))) short short8;
typedef __attribute__((ext_vector_type(4))) float floatx4;

__device__ inline unsigned short f2bf(float f) {
  unsigned u = __float_as_uint(f);
  unsigned r = (u + 0x7fffu + ((u >> 16) & 1u)) >> 16;  // RNE
  return (unsigned short)r;
}

__device__ __forceinline__ float fast_exp2(float x) {
#if __has_builtin(__builtin_amdgcn_exp2f)
  return __builtin_amdgcn_exp2f(x);
#else
  float r;
  asm volatile("v_exp_f32_e32 %0, %1" : "=v"(r) : "v"(x));
  return r;
#endif
}

__device__ __forceinline__ void gll16(const unsigned short* g, unsigned short* l) {
  __builtin_amdgcn_global_load_lds(
      (const __attribute__((address_space(1))) unsigned int*)(g),
      (__attribute__((address_space(3))) unsigned int*)(l),
      16, 0, 0);
}

constexpr int B_ = 2, S_ = 2048, D_ = 1024, H_ = 16, HD_ = 64;

// ---------------------------------------------------------------------------
// Merged one-time converter: z=0..3 -> W transpose+convert; z=4 -> X convert.
// ---------------------------------------------------------------------------
__global__ __launch_bounds__(256) void prep_inputs(
    const float* __restrict__ x, unsigned short* __restrict__ xb,
    const float* __restrict__ w0, const float* __restrict__ w1,
    const float* __restrict__ w2, const float* __restrict__ w3,
    unsigned short* __restrict__ wt_base)
{
  if (blockIdx.z == 4) {
    const int tid = threadIdx.y * 32 + threadIdx.x;
    const size_t base =
        ((size_t)(blockIdx.y * 32 + blockIdx.x) * 256 + tid) * 16;
#pragma unroll
    for (int half = 0; half < 2; ++half) {
      const size_t i = base + half * 8;
      float4 a = *(const float4*)(x + i);
      float4 b = *(const float4*)(x + i + 4);
      short8 o;
      o[0] = (short)f2bf(a.x); o[1] = (short)f2bf(a.y);
      o[2] = (short)f2bf(a.z); o[3] = (short)f2bf(a.w);
      o[4] = (short)f2bf(b.x); o[5] = (short)f2bf(b.y);
      o[6] = (short)f2bf(b.z); o[7] = (short)f2bf(b.w);
      *(short8*)(xb + i) = o;
    }
    return;
  }
  const float* src;
  switch (blockIdx.z) {
    case 0: src = w0; break;
    case 1: src = w1; break;
    case 2: src = w2; break;
    default: src = w3; break;
  }
  unsigned short* dst = wt_base + (size_t)blockIdx.z * 1024 * 1024;
  __shared__ unsigned short t[32][33];
  const int bx = blockIdx.x * 32;  // n
  const int by = blockIdx.y * 32;  // k
  const int x_ = threadIdx.x;
  for (int yy = threadIdx.y; yy < 32; yy += 8)
    t[yy][x_] = f2bf(src[(size_t)(by + yy) * 1024 + bx + x_]);
  __syncthreads();
  for (int yy = threadIdx.y; yy < 32; yy += 8)
    dst[(size_t)(bx + yy) * 1024 + by + x_] = t[x_][yy];
}

// Vb[b][s][h*64+d] bf16 -> Vt[(b*16+h)*64+d][s] bf16
__global__ __launch_bounds__(256) void transpose_v(
    const unsigned short* __restrict__ Vb, unsigned short* __restrict__ Vt)
{
  __shared__ unsigned short t[32][33];
  const int bh = blockIdx.z;
  const int b = bh >> 4, h = bh & 15;
  const int s0 = blockIdx.x * 32, d0 = blockIdx.y * 32;
  const int x = threadIdx.x;
  for (int yy = threadIdx.y; yy < 32; yy += 8)
    t[yy][x] = Vb[(size_t)(b * 2048 + s0 + yy) * 1024 + h * 64 + d0 + x];
  __syncthreads();
  for (int yy = threadIdx.y; yy < 32; yy += 8)
    Vt[((size_t)bh * 64 + d0 + yy) * 2048 + s0 + x] = t[x][yy];
}

// ---------------------------------------------------------------------------
// QKV GEMM (unchanged): 128x128 tile, BK=64 two-subtile staging.
// ---------------------------------------------------------------------------
__global__ __launch_bounds__(256) void gemm256_qkv(
    const unsigned short* __restrict__ A,
    const unsigned short* __restrict__ Bt,
    unsigned short* __restrict__ Qo,
    unsigned short* __restrict__ Ko,
    unsigned short* __restrict__ Vo)
{
  __shared__ unsigned short sA[2][128 * 32];
  __shared__ unsigned short sB[2][128 * 32];
  const int K = 1024;
  const int m0 = blockIdx.y * 128;
  const int bn0 = blockIdx.x * 128;

  const int tid = threadIdx.x, wave = tid >> 6, lane = tid & 63;
  const int g = lane >> 4, ml = lane & 15;
  const int wm = wave & 1, wn = wave >> 1;

  const unsigned short* ag0 = A + (size_t)(m0 + (tid >> 2)) * K + (tid & 3) * 8;
  const unsigned short* ag1 = ag0 + (size_t)64 * K;
  const unsigned short* bg0 = Bt + (size_t)(bn0 + (tid >> 2)) * K + (tid & 3) * 8;
  const unsigned short* bg1 = bg0 + (size_t)64 * K;
  const int woff = wave * 512;

  floatx4 acc[4][4];
#pragma unroll
  for (int mt = 0; mt < 4; ++mt)
#pragma unroll
    for (int nt = 0; nt < 4; ++nt) acc[mt][nt] = (floatx4){0.f, 0.f, 0.f, 0.f};

  for (int k0 = 0; k0 < K; k0 += 64) {
    __syncthreads();
#pragma unroll
    for (int t = 0; t < 2; ++t) {
      gll16(ag0 + k0 + t * 32, sA[t] + woff);
      gll16(ag1 + k0 + t * 32, sA[t] + 2048 + woff);
      gll16(bg0 + k0 + t * 32, sB[t] + woff);
      gll16(bg1 + k0 + t * 32, sB[t] + 2048 + woff);
    }
    __syncthreads();
#pragma unroll
    for (int t = 0; t < 2; ++t) {
      short8 af[4], bf[4];
#pragma unroll
      for (int mt = 0; mt < 4; ++mt)
        af[mt] = *(const short8*)(sA[t] + (wm * 64 + mt * 16 + ml) * 32 + g * 8);
#pragma unroll
      for (int nt = 0; nt < 4; ++nt)
        bf[nt] = *(const short8*)(sB[t] + (wn * 64 + nt * 16 + ml) * 32 + g * 8);
#pragma unroll
      for (int mt = 0; mt < 4; ++mt)
#pragma unroll
        for (int nt = 0; nt < 4; ++nt)
          acc[mt][nt] = __builtin_amdgcn_mfma_f32_16x16x32_bf16(
              af[mt], bf[nt], acc[mt][nt], 0, 0, 0);
    }
  }

  const int proj = blockIdx.x >> 3;
  unsigned short* out = (proj == 0) ? Qo : (proj == 1) ? Ko : Vo;
  const int col0 = (blockIdx.x & 7) * 128;
#pragma unroll
  for (int mt = 0; mt < 4; ++mt) {
#pragma unroll
    for (int nt = 0; nt < 4; ++nt) {
      const int col = col0 + wn * 64 + nt * 16 + ml;
#pragma unroll
      for (int r = 0; r < 4; ++r) {
        const int row = m0 + wm * 64 + mt * 16 + g * 4 + r;
        out[(size_t)row * 1024 + col] = f2bf(acc[mt][nt][r]);
      }
    }
  }
}

// Output projection, 64x128 tile, BK=128 four-subtile staging (8 stages).
__global__ __launch_bounds__(256) void gemm_wo64(
    const unsigned short* __restrict__ A,
    const unsigned short* __restrict__ Bt,
    const float* __restrict__ bias,
    float* __restrict__ C)
{
  __shared__ unsigned short sA[4][64 * 32];
  __shared__ unsigned short sB[4][128 * 32];
  const int K = 1024;
  const int m0 = blockIdx.y * 64;
  const int bn0 = blockIdx.x * 128;
  const int tid = threadIdx.x, wave = tid >> 6, lane = tid & 63;
  const int g = lane >> 4, ml = lane & 15;
  const int wm = wave & 1, wn = wave >> 1;

  const unsigned short* ag =
      A + (size_t)(m0 + wave * 16 + (lane >> 2)) * K + (lane & 3) * 8;
  const unsigned short* bg0 = Bt + (size_t)(bn0 + (tid >> 2)) * K + (tid & 3) * 8;
  const unsigned short* bg1 = bg0 + (size_t)64 * K;
  const int woff = wave * 512;

  floatx4 acc[2][4];
#pragma unroll
  for (int mt = 0; mt < 2; ++mt)
#pragma unroll
    for (int nt = 0; nt < 4; ++nt) acc[mt][nt] = (floatx4){0.f, 0.f, 0.f, 0.f};

  for (int k0 = 0; k0 < K; k0 += 128) {
    __syncthreads();
#pragma unroll
    for (int t = 0; t < 4; ++t) {
      gll16(ag + k0 + t * 32, sA[t] + woff);
      gll16(bg0 + k0 + t * 32, sB[t] + woff);
      gll16(bg1 + k0 + t * 32, sB[t] + 2048 + woff);
    }
    __syncthreads();
#pragma unroll
    for (int t = 0; t < 4; ++t) {
      short8 af[2], bf[4];
#pragma unroll
      for (int mt = 0; mt < 2; ++mt)
        af[mt] = *(const short8*)(sA[t] + (wm * 32 + mt * 16 + ml) * 32 + g * 8);
#pragma unroll
      for (int nt = 0; nt < 4; ++nt)
        bf[nt] = *(const short8*)(sB[t] + (wn * 64 + nt * 16 + ml) * 32 + g * 8);
#pragma unroll
      for (int mt = 0; mt < 2; ++mt)
#pragma unroll
        for (int nt = 0; nt < 4; ++nt)
          acc[mt][nt] = __builtin_amdgcn_mfma_f32_16x16x32_bf16(
              af[mt], bf[nt], acc[mt][nt], 0, 0, 0);
    }
  }

#pragma unroll
  for (int mt = 0; mt < 2; ++mt) {
#pragma unroll
    for (int nt = 0; nt < 4; ++nt) {
      const int col = bn0 + wn * 64 + nt * 16 + ml;
      const float badd = bias[col];
#pragma unroll
      for (int r = 0; r < 4; ++r) {
        const int row = m0 + wm * 32 + mt * 16 + g * 4 + r;
        C[(size_t)row * 1024 + col] = acc[mt][nt][r] + badd;
      }
    }
  }
}

// ---------------------------------------------------------------------------
// Attention v15: v13 (passing) + fused A/B tile compute ONLY.
// K/V fragments read once per tile, feed both q-blocks' MFMA chains.
// NO LDS swizzle, NO launch_bounds min-occupancy arg (exact v13 config).
// LDS: 2 bufs x 2 tiles x (K 8KB + V 8KB) = 64KB; union comb 36KB.
// ---------------------------------------------------------------------------
constexpr int KTPB = 2;  // k-tiles per buffer group

struct AttnLds {
  unsigned short k0[2][KTPB][64 * 32];
  unsigned short k1[2][KTPB][64 * 32];
  unsigned short v0[2][KTPB][64 * 32];
  unsigned short v1[2][KTPB][64 * 32];
};
union __align__(16) AttnLdsU {
  AttnLds t;
  float comb[4 * 64 * 36];  // 36 KB <= 64 KB; used after last barrier
};

// softmax + truncate + pack + permlane redistribute: s -> ap[2] (PV A-frags)
__device__ __forceinline__ void softmax_pack(
    const floatx4* s, const bool diag, const int qg, const int kb,
    float& l, short8* ap)
{
  const float C1 = 0.18033688f;    // 0.125 / ln2
  const float C2 = -34.6246810f;   // -24 / ln2

  unsigned wb[4][4];
#pragma unroll
  for (int nb = 0; nb < 4; ++nb) {
#pragma unroll
    for (int r = 0; r < 4; ++r) {
      float wv = fast_exp2(fmaf(s[nb][r], C1, C2));
      if (diag && (kb + nb * 16 + r > qg)) wv = 0.f;
      const unsigned bits = __float_as_uint(wv) & 0xffff0000u;
      wb[nb][r] = bits;
      l += __uint_as_float(bits);
    }
  }

  // pack pairs along r (v_perm bytes 2,3 of each source = truncated bf16)
  unsigned pk[4][2];
#pragma unroll
  for (int nb = 0; nb < 4; ++nb) {
    pk[nb][0] = __builtin_amdgcn_perm(wb[nb][1], wb[nb][0], 0x07060302u);
    pk[nb][1] = __builtin_amdgcn_perm(wb[nb][3], wb[nb][2], 0x07060302u);
  }

  // redistribute to PV A-frag: 2x permlane32_swap + 2x permlane16_swap per rr
  unsigned Fr[2][4];
#pragma unroll
  for (int rr = 0; rr < 2; ++rr) {
    unsigned a0 = pk[0][rr], a1 = pk[1][rr];
    unsigned a2 = pk[2][rr], a3 = pk[3][rr];
    asm("v_permlane32_swap_b32 %0, %1" : "+v"(a0), "+v"(a1));
    asm("v_permlane32_swap_b32 %0, %1" : "+v"(a2), "+v"(a3));
    asm("v_permlane16_swap_b32 %0, %1" : "+v"(a0), "+v"(a1));
    asm("v_permlane16_swap_b32 %0, %1" : "+v"(a2), "+v"(a3));
    Fr[0][rr] = a0; Fr[0][2 + rr] = a1;
    Fr[1][rr] = a2; Fr[1][2 + rr] = a3;
  }
#pragma unroll
  for (int f = 0; f < 2; ++f) {
    union { unsigned u[4]; short8 s8; } uap;
    uap.u[0] = Fr[f][0]; uap.u[1] = Fr[f][1];
    uap.u[2] = Fr[f][2]; uap.u[3] = Fr[f][3];
    ap[f] = uap.s8;
  }
}

// Fused dual-q-block tile: K/V fragments read ONCE, feed both MFMA chains.
template <bool DUAL>
__device__ __forceinline__ void attn_tile2(
    const short8* aqB, const short8* aqA,
    const unsigned short* sK0, const unsigned short* sK1,
    const unsigned short* sV0, const unsigned short* sV1,
    floatx4* accB, float& lB, floatx4* accA, float& lA,
    const bool diagB, const bool diagA,
    const int qgB, const int qgA, const int kb,
    const int g, const int ml)
{
  floatx4 sB[4], sA[4];
#pragma unroll
  for (int nb = 0; nb < 4; ++nb) {
    short8 bk0 = *(const short8*)(sK0 + (nb * 16 + ml) * 32 + g * 8);
    short8 bk1 = *(const short8*)(sK1 + (nb * 16 + ml) * 32 + g * 8);
    sB[nb] = (floatx4){0.f, 0.f, 0.f, 0.f};
    sB[nb] = __builtin_amdgcn_mfma_f32_16x16x32_bf16(bk0, aqB[0], sB[nb], 0, 0, 0);
    sB[nb] = __builtin_amdgcn_mfma_f32_16x16x32_bf16(bk1, aqB[1], sB[nb], 0, 0, 0);
    if (DUAL) {
      sA[nb] = (floatx4){0.f, 0.f, 0.f, 0.f};
      sA[nb] = __builtin_amdgcn_mfma_f32_16x16x32_bf16(bk0, aqA[0], sA[nb], 0, 0, 0);
      sA[nb] = __builtin_amdgcn_mfma_f32_16x16x32_bf16(bk1, aqA[1], sA[nb], 0, 0, 0);
    }
  }

  short8 apB[2], apA[2];
  softmax_pack(sB, diagB, qgB, kb, lB, apB);
  if (DUAL) softmax_pack(sA, diagA, qgA, kb, lA, apA);

#pragma unroll
  for (int f = 0; f < 2; ++f) {
    const unsigned short* sv = f ? sV1 : sV0;
#pragma unroll
    for (int jd = 0; jd < 4; ++jd) {
      short8 bv = *(const short8*)(sv + (jd * 16 + ml) * 32 + g * 8);
      accB[jd] = __builtin_amdgcn_mfma_f32_16x16x32_bf16(apB[f], bv, accB[jd], 0, 0, 0);
      if (DUAL)
        accA[jd] = __builtin_amdgcn_mfma_f32_16x16x32_bf16(apA[f], bv, accA[jd], 0, 0, 0);
    }
  }
}

__global__ __launch_bounds__(512) void attn_v15(
    const unsigned short* __restrict__ Q,
    const unsigned short* __restrict__ Kg,
    const unsigned short* __restrict__ Vt,
    unsigned short* __restrict__ CTX)
{
  __shared__ AttnLdsU lds;

  // XCD-chunked swizzle (bijective: 512 % 8 == 0): groups 4 consecutive bh
  // per XCD -> K/V working set 2MB < 4MB L2.
  const int L = blockIdx.x;
  const int rid = (L & 7) * 64 + (L >> 3);
  const int p = rid & 15;
  const int bh = rid >> 4;

  const int b = bh >> 4, h = bh & 15;
  const int qbA = p, qbB = 31 - p;
  const int qA0 = qbA * 64, qB0 = qbB * 64;
  const int tid = threadIdx.x, w = tid >> 6, lane = tid & 63;
  const int slice = w & 3, par = w >> 2;
  const int g = lane >> 4, ml = lane & 15;

  const size_t headoff = (size_t)b * S_ * D_ + (size_t)h * HD_;
  const size_t vtoff   = (size_t)bh * HD_ * S_;

  short8 aqA[2], aqB[2];
  {
    const unsigned short* qp =
        Q + headoff + (size_t)(qA0 + slice * 16 + ml) * D_ + g * 8;
    aqA[0] = *(const short8*)qp;
    aqA[1] = *(const short8*)(qp + 32);
  }
  {
    const unsigned short* qp =
        Q + headoff + (size_t)(qB0 + slice * 16 + ml) * D_ + g * 8;
    aqB[0] = *(const short8*)qp;
    aqB[1] = *(const short8*)(qp + 32);
  }

  floatx4 accA[4], accB[4];
#pragma unroll
  for (int jd = 0; jd < 4; ++jd) {
    accA[jd] = (floatx4){0.f, 0.f, 0.f, 0.f};
    accB[jd] = (floatx4){0.f, 0.f, 0.f, 0.f};
  }
  float lA = 0.f, lB = 0.f;
  const int qgA = qA0 + slice * 16 + ml;   // this lane's q-row (A block)
  const int qgB = qB0 + slice * 16 + ml;

  // staging: waves 0-3 handle K, waves 4-7 handle V; each covers 16 rows.
  const int sw = slice;
  const unsigned short* kgb =
      Kg + headoff + (size_t)(sw * 16 + (lane >> 2)) * D_ + (lane & 3) * 8;
  const unsigned short* vgb =
      Vt + vtoff + (size_t)(sw * 16 + (lane >> 2)) * S_ + (lane & 3) * 8;
  const int woff = sw * 512;

  const int ntiles = qbB + 1;

  // ---- stage group 0 into buf 0 (prologue; one unhidden drain) ----
  {
    const int cnt = (ntiles < KTPB) ? ntiles : KTPB;
#pragma unroll
    for (int t = 0; t < KTPB; ++t) {
      if (t >= cnt) break;
      if (w < 4) {
        const size_t ko = (size_t)t * 64 * D_;
        gll16(kgb + ko,      lds.t.k0[0][t] + woff);
        gll16(kgb + ko + 32, lds.t.k1[0][t] + woff);
      } else {
        gll16(vgb + t * 64,      lds.t.v0[0][t] + woff);
        gll16(vgb + t * 64 + 32, lds.t.v1[0][t] + woff);
      }
    }
  }
  __syncthreads();

  for (int kt0 = 0; kt0 < ntiles; kt0 += KTPB) {
    const int bufi = (kt0 >> 1) & 1;
    // ---- stage NEXT group into buf^1 (issue early; drained at barrier) ----
    const int nxt = kt0 + KTPB;
    if (nxt < ntiles) {
      const int cn = (ntiles - nxt < KTPB) ? (ntiles - nxt) : KTPB;
#pragma unroll
      for (int t = 0; t < KTPB; ++t) {
        if (t >= cn) break;
        const int kt = nxt + t;
        if (w < 4) {
          const size_t ko = (size_t)kt * 64 * D_;
          gll16(kgb + ko,      lds.t.k0[bufi ^ 1][t] + woff);
          gll16(kgb + ko + 32, lds.t.k1[bufi ^ 1][t] + woff);
        } else {
          gll16(vgb + kt * 64,      lds.t.v0[bufi ^ 1][t] + woff);
          gll16(vgb + kt * 64 + 32, lds.t.v1[bufi ^ 1][t] + woff);
        }
      }
    }

    // ---- compute current buf (A/B fused when both in causal range) ----
    const int cnt = (ntiles - kt0 < KTPB) ? (ntiles - kt0) : KTPB;  // uniform
    if (par < cnt) {
      const int kt = kt0 + par;
      const int kb = kt * 64 + g * 4;
      if (kt <= qbA)
        attn_tile2<true>(aqB, aqA,
                         lds.t.k0[bufi][par], lds.t.k1[bufi][par],
                         lds.t.v0[bufi][par], lds.t.v1[bufi][par],
                         accB, lB, accA, lA,
                         kt == qbB, kt == qbA, qgB, qgA, kb, g, ml);
      else
        attn_tile2<false>(aqB, aqA,
                          lds.t.k0[bufi][par], lds.t.k1[bufi][par],
                          lds.t.v0[bufi][par], lds.t.v1[bufi][par],
                          accB, lB, accA, lA,
                          kt == qbB, false, qgB, qgA, kb, g, ml);
    }
    __syncthreads();  // drains next-group loads (hidden under compute)
  }

  // ---- combine parity pairs (w, w+4) through LDS ----
  {
    float* slot = lds.comb + (size_t)(slice * 64 + lane) * 36;
    if (par == 1) {
#pragma unroll
      for (int jd = 0; jd < 4; ++jd) {
        *(floatx4*)(slot + jd * 4) = accA[jd];
        *(floatx4*)(slot + 16 + jd * 4) = accB[jd];
      }
      slot[32] = lA;
      slot[33] = lB;
    }
    __syncthreads();
    if (par == 1) return;  // upper waves done; no further barriers below
#pragma unroll
    for (int jd = 0; jd < 4; ++jd) {
      accA[jd] += *(const floatx4*)(slot + jd * 4);
      accB[jd] += *(const floatx4*)(slot + 16 + jd * 4);
    }
    lA += slot[32];
    lB += slot[33];
  }

  // reduce l across the 4 lanes sharing ml (k was spread over g), invert,
  // then fetch per-output-row values (row = g*4+r lives at lane ml=g*4+r).
  lA += __shfl_xor(lA, 16); lA += __shfl_xor(lA, 32);
  lB += __shfl_xor(lB, 16); lB += __shfl_xor(lB, 32);
  const float liA = 1.0f / lA;
  const float liB = 1.0f / lB;
  float lrA[4], lrB[4];
#pragma unroll
  for (int r = 0; r < 4; ++r) {
    lrA[r] = __shfl(liA, g * 4 + r);
    lrB[r] = __shfl(liB, g * 4 + r);
  }

#pragma unroll
  for (int r = 0; r < 4; ++r) {
    const int rowA = qA0 + slice * 16 + g * 4 + r;
    const int rowB = qB0 + slice * 16 + g * 4 + r;
#pragma unroll
    for (int jd = 0; jd < 4; ++jd) {
      CTX[headoff + (size_t)rowA * D_ + jd * 16 + ml] = f2bf(accA[jd][r] * lrA[r]);
      CTX[headoff + (size_t)rowB * D_ + jd * 16 + ml] = f2bf(accB[jd][r] * lrB[r]);
    }
  }
}

// ---------------------------------------------------------------------------
extern "C" void kernel_launch(void* const* d_in, const int* in_sizes, int n_in,
                              void* d_out, int out_size, void* d_ws, size_t ws_size,
                              hipStream_t stream)
{
  const float* X  = (const float*)d_in[0];
  const float* Wq = (const float*)d_in[1];
  const float* Wk = (const float*)d_in[2];
  const float* Wv = (const float*)d_in[3];
  const float* Wo = (const float*)d_in[4];
  const float* bo = (const float*)d_in[5];

  char* ws = (char*)d_ws;
  const size_t MB = 1024 * 1024;

  unsigned short* Qb  = (unsigned short*)(ws);            // 8 MB (CTX aliases)
  unsigned short* Kb  = (unsigned short*)(ws + 8 * MB);   // 8 MB
  unsigned short* Xb  = (unsigned short*)(ws + 16 * MB);  // 8 MB; Vt after QKV
  unsigned short* WT  = (unsigned short*)(ws + 24 * MB);  // WqT|WkT|WvT|WoT
  unsigned short* WoT = WT + (size_t)3 * 1024 * 1024;
  unsigned short* Vb  = (unsigned short*)d_out;           // low 8MB of d_out
  unsigned short* Vt  = Xb;                               // reuse dead Xb

  // merged X-convert (z=4) + 4x W transpose/convert (z=0..3)
  prep_inputs<<<dim3(32, 32, 5), dim3(32, 8), 0, stream>>>(
      X, Xb, Wq, Wk, Wv, Wo, WT);
  // fused Q/K/V projection: Bt = WT[0..3071][1024], BK=64 staging
  gemm256_qkv<<<dim3(24, 32), 256, 0, stream>>>(Xb, WT, Qb, Kb, Vb);
  // V -> Vt[(b*16+h)*64+d][s]  (Xb dead now)
  transpose_v<<<dim3(64, 2, 32), dim3(32, 8), 0, stream>>>(Vb, Vt);
  // fused A/B, 2-phase pipelined, XCD-swizzled attention; CTX aliases Q
  attn_v15<<<dim3(512), 512, 0, stream>>>(Qb, Kb, Vt, Qb);
  // output projection + bias (64x128 tile, BK=128, 512 blocks)
  gemm_wo64<<<dim3(8, 64), 256, 0, stream>>>(Qb, WoT, bo, (float*)d_out);
}

// Round 6
// 183.584 us; speedup vs baseline: 1.1196x; 1.0082x over previous
//
#include <hip/hip_runtime.h>

// MultiHeadAttention: B=2, S=2048, D=1024, H=16, hd=64. fp32 I/O.
// Round 22: three additive low-risk levers.
// (1) attn softmax: l sums RAW f32 wv in 4 per-nb partials (serial chain
//     16 -> 4+3; drops all 16 v_and per pack; v_perm byte-select already
//     truncates P). Numerics: l >= sum(trunc) by <2^-9 rel -- inside thr.
// (2) attn: s_setprio(1) around QK and PV MFMA clusters (T5, +4-7% attn).
// (3) Both GEMMs get bijective XCD-chunked block swizzle (T1): qkv 4 row-
//     panels x 24 cols per XCD (A-panel 1MB L2-resident); wo64 8x8.
// R21 base kept: fused A/B dual-tile, 2-phase pipeline, XCD-swizzled attn,
// in-register softmax. NO LDS layout changes (R20 lesson).

typedef __attribute__((ext_vector_type(8))) short short8;
typedef __attribute__((ext_vector_type(4))) float floatx4;

__device__ inline unsigned short f2bf(float f) {
  unsigned u = __float_as_uint(f);
  unsigned r = (u + 0x7fffu + ((u >> 16) & 1u)) >> 16;  // RNE
  return (unsigned short)r;
}

__device__ __forceinline__ float fast_exp2(float x) {
#if __has_builtin(__builtin_amdgcn_exp2f)
  return __builtin_amdgcn_exp2f(x);
#else
  float r;
  asm volatile("v_exp_f32_e32 %0, %1" : "=v"(r) : "v"(x));
  return r;
#endif
}

__device__ __forceinline__ void gll16(const unsigned short* g, unsigned short* l) {
  __builtin_amdgcn_global_load_lds(
      (const __attribute__((address_space(1))) unsigned int*)(g),
      (__attribute__((address_space(3))) unsigned int*)(l),
      16, 0, 0);
}

constexpr int B_ = 2, S_ = 2048, D_ = 1024, H_ = 16, HD_ = 64;

// ---------------------------------------------------------------------------
// Merged one-time converter: z=0..3 -> W transpose+convert; z=4 -> X convert.
// ---------------------------------------------------------------------------
__global__ __launch_bounds__(256) void prep_inputs(
    const float* __restrict__ x, unsigned short* __restrict__ xb,
    const float* __restrict__ w0, const float* __restrict__ w1,
    const float* __restrict__ w2, const float* __restrict__ w3,
    unsigned short* __restrict__ wt_base)
{
  if (blockIdx.z == 4) {
    const int tid = threadIdx.y * 32 + threadIdx.x;
    const size_t base =
        ((size_t)(blockIdx.y * 32 + blockIdx.x) * 256 + tid) * 16;
#pragma unroll
    for (int half = 0; half < 2; ++half) {
      const size_t i = base + half * 8;
      float4 a = *(const float4*)(x + i);
      float4 b = *(const float4*)(x + i + 4);
      short8 o;
      o[0] = (short)f2bf(a.x); o[1] = (short)f2bf(a.y);
      o[2] = (short)f2bf(a.z); o[3] = (short)f2bf(a.w);
      o[4] = (short)f2bf(b.x); o[5] = (short)f2bf(b.y);
      o[6] = (short)f2bf(b.z); o[7] = (short)f2bf(b.w);
      *(short8*)(xb + i) = o;
    }
    return;
  }
  const float* src;
  switch (blockIdx.z) {
    case 0: src = w0; break;
    case 1: src = w1; break;
    case 2: src = w2; break;
    default: src = w3; break;
  }
  unsigned short* dst = wt_base + (size_t)blockIdx.z * 1024 * 1024;
  __shared__ unsigned short t[32][33];
  const int bx = blockIdx.x * 32;  // n
  const int by = blockIdx.y * 32;  // k
  const int x_ = threadIdx.x;
  for (int yy = threadIdx.y; yy < 32; yy += 8)
    t[yy][x_] = f2bf(src[(size_t)(by + yy) * 1024 + bx + x_]);
  __syncthreads();
  for (int yy = threadIdx.y; yy < 32; yy += 8)
    dst[(size_t)(bx + yy) * 1024 + by + x_] = t[x_][yy];
}

// Vb[b][s][h*64+d] bf16 -> Vt[(b*16+h)*64+d][s] bf16
__global__ __launch_bounds__(256) void transpose_v(
    const unsigned short* __restrict__ Vb, unsigned short* __restrict__ Vt)
{
  __shared__ unsigned short t[32][33];
  const int bh = blockIdx.z;
  const int b = bh >> 4, h = bh & 15;
  const int s0 = blockIdx.x * 32, d0 = blockIdx.y * 32;
  const int x = threadIdx.x;
  for (int yy = threadIdx.y; yy < 32; yy += 8)
    t[yy][x] = Vb[(size_t)(b * 2048 + s0 + yy) * 1024 + h * 64 + d0 + x];
  __syncthreads();
  for (int yy = threadIdx.y; yy < 32; yy += 8)
    Vt[((size_t)bh * 64 + d0 + yy) * 2048 + s0 + x] = t[x][yy];
}

// ---------------------------------------------------------------------------
// QKV GEMM: 128x128 tile, BK=64 two-subtile staging + XCD-chunked swizzle.
// ---------------------------------------------------------------------------
__global__ __launch_bounds__(256) void gemm256_qkv(
    const unsigned short* __restrict__ A,
    const unsigned short* __restrict__ Bt,
    unsigned short* __restrict__ Qo,
    unsigned short* __restrict__ Ko,
    unsigned short* __restrict__ Vo)
{
  __shared__ unsigned short sA[2][128 * 32];
  __shared__ unsigned short sB[2][128 * 32];
  const int K = 1024;

  // XCD swizzle (bijective: 768 % 8 == 0): each XCD owns 4 row-panels x
  // all 24 col-blocks -> A-panel (1MB) L2-resident across its col-blocks.
  const int L = blockIdx.y * 24 + blockIdx.x;
  const int rid = (L & 7) * 96 + (L >> 3);
  const int brow = rid / 24, bcol = rid % 24;
  const int m0 = brow * 128;
  const int bn0 = bcol * 128;

  const int tid = threadIdx.x, wave = tid >> 6, lane = tid & 63;
  const int g = lane >> 4, ml = lane & 15;
  const int wm = wave & 1, wn = wave >> 1;

  const unsigned short* ag0 = A + (size_t)(m0 + (tid >> 2)) * K + (tid & 3) * 8;
  const unsigned short* ag1 = ag0 + (size_t)64 * K;
  const unsigned short* bg0 = Bt + (size_t)(bn0 + (tid >> 2)) * K + (tid & 3) * 8;
  const unsigned short* bg1 = bg0 + (size_t)64 * K;
  const int woff = wave * 512;

  floatx4 acc[4][4];
#pragma unroll
  for (int mt = 0; mt < 4; ++mt)
#pragma unroll
    for (int nt = 0; nt < 4; ++nt) acc[mt][nt] = (floatx4){0.f, 0.f, 0.f, 0.f};

  for (int k0 = 0; k0 < K; k0 += 64) {
    __syncthreads();
#pragma unroll
    for (int t = 0; t < 2; ++t) {
      gll16(ag0 + k0 + t * 32, sA[t] + woff);
      gll16(ag1 + k0 + t * 32, sA[t] + 2048 + woff);
      gll16(bg0 + k0 + t * 32, sB[t] + woff);
      gll16(bg1 + k0 + t * 32, sB[t] + 2048 + woff);
    }
    __syncthreads();
#pragma unroll
    for (int t = 0; t < 2; ++t) {
      short8 af[4], bf[4];
#pragma unroll
      for (int mt = 0; mt < 4; ++mt)
        af[mt] = *(const short8*)(sA[t] + (wm * 64 + mt * 16 + ml) * 32 + g * 8);
#pragma unroll
      for (int nt = 0; nt < 4; ++nt)
        bf[nt] = *(const short8*)(sB[t] + (wn * 64 + nt * 16 + ml) * 32 + g * 8);
#pragma unroll
      for (int mt = 0; mt < 4; ++mt)
#pragma unroll
        for (int nt = 0; nt < 4; ++nt)
          acc[mt][nt] = __builtin_amdgcn_mfma_f32_16x16x32_bf16(
              af[mt], bf[nt], acc[mt][nt], 0, 0, 0);
    }
  }

  const int proj = bcol >> 3;
  unsigned short* out = (proj == 0) ? Qo : (proj == 1) ? Ko : Vo;
  const int col0 = (bcol & 7) * 128;
#pragma unroll
  for (int mt = 0; mt < 4; ++mt) {
#pragma unroll
    for (int nt = 0; nt < 4; ++nt) {
      const int col = col0 + wn * 64 + nt * 16 + ml;
#pragma unroll
      for (int r = 0; r < 4; ++r) {
        const int row = m0 + wm * 64 + mt * 16 + g * 4 + r;
        out[(size_t)row * 1024 + col] = f2bf(acc[mt][nt][r]);
      }
    }
  }
}

// Output projection, 64x128 tile, BK=128 four-subtile staging + XCD swizzle.
__global__ __launch_bounds__(256) void gemm_wo64(
    const unsigned short* __restrict__ A,
    const unsigned short* __restrict__ Bt,
    const float* __restrict__ bias,
    float* __restrict__ C)
{
  __shared__ unsigned short sA[4][64 * 32];
  __shared__ unsigned short sB[4][128 * 32];
  const int K = 1024;

  // XCD swizzle (bijective: 512 % 8 == 0): 8 row-panels x 8 cols per XCD
  // (A 1MB + WoT 2MB fit L2).
  const int L = blockIdx.y * 8 + blockIdx.x;
  const int rid = (L & 7) * 64 + (L >> 3);
  const int m0 = (rid >> 3) * 64;
  const int bn0 = (rid & 7) * 128;

  const int tid = threadIdx.x, wave = tid >> 6, lane = tid & 63;
  const int g = lane >> 4, ml = lane & 15;
  const int wm = wave & 1, wn = wave >> 1;

  const unsigned short* ag =
      A + (size_t)(m0 + wave * 16 + (lane >> 2)) * K + (lane & 3) * 8;
  const unsigned short* bg0 = Bt + (size_t)(bn0 + (tid >> 2)) * K + (tid & 3) * 8;
  const unsigned short* bg1 = bg0 + (size_t)64 * K;
  const int woff = wave * 512;

  floatx4 acc[2][4];
#pragma unroll
  for (int mt = 0; mt < 2; ++mt)
#pragma unroll
    for (int nt = 0; nt < 4; ++nt) acc[mt][nt] = (floatx4){0.f, 0.f, 0.f, 0.f};

  for (int k0 = 0; k0 < K; k0 += 128) {
    __syncthreads();
#pragma unroll
    for (int t = 0; t < 4; ++t) {
      gll16(ag + k0 + t * 32, sA[t] + woff);
      gll16(bg0 + k0 + t * 32, sB[t] + woff);
      gll16(bg1 + k0 + t * 32, sB[t] + 2048 + woff);
    }
    __syncthreads();
#pragma unroll
    for (int t = 0; t < 4; ++t) {
      short8 af[2], bf[4];
#pragma unroll
      for (int mt = 0; mt < 2; ++mt)
        af[mt] = *(const short8*)(sA[t] + (wm * 32 + mt * 16 + ml) * 32 + g * 8);
#pragma unroll
      for (int nt = 0; nt < 4; ++nt)
        bf[nt] = *(const short8*)(sB[t] + (wn * 64 + nt * 16 + ml) * 32 + g * 8);
#pragma unroll
      for (int mt = 0; mt < 2; ++mt)
#pragma unroll
        for (int nt = 0; nt < 4; ++nt)
          acc[mt][nt] = __builtin_amdgcn_mfma_f32_16x16x32_bf16(
              af[mt], bf[nt], acc[mt][nt], 0, 0, 0);
    }
  }

#pragma unroll
  for (int mt = 0; mt < 2; ++mt) {
#pragma unroll
    for (int nt = 0; nt < 4; ++nt) {
      const int col = bn0 + wn * 64 + nt * 16 + ml;
      const float badd = bias[col];
#pragma unroll
      for (int r = 0; r < 4; ++r) {
        const int row = m0 + wm * 32 + mt * 16 + g * 4 + r;
        C[(size_t)row * 1024 + col] = acc[mt][nt][r] + badd;
      }
    }
  }
}

// ---------------------------------------------------------------------------
// Attention v16: v15 + raw-f32 l partials (no v_and, 4-way chain) + setprio.
// LDS: 2 bufs x 2 tiles x (K 8KB + V 8KB) = 64KB; union comb 36KB.
// ---------------------------------------------------------------------------
constexpr int KTPB = 2;  // k-tiles per buffer group

struct AttnLds {
  unsigned short k0[2][KTPB][64 * 32];
  unsigned short k1[2][KTPB][64 * 32];
  unsigned short v0[2][KTPB][64 * 32];
  unsigned short v1[2][KTPB][64 * 32];
};
union __align__(16) AttnLdsU {
  AttnLds t;
  float comb[4 * 64 * 36];  // 36 KB <= 64 KB; used after last barrier
};

// softmax + pack + permlane redistribute: s -> ap[2] (PV A-frags).
// l sums RAW f32 (4 partials); v_perm byte-select truncates P to bf16.
__device__ __forceinline__ void softmax_pack(
    const floatx4* s, const bool diag, const int qg, const int kb,
    float& l, short8* ap)
{
  const float C1 = 0.18033688f;    // 0.125 / ln2
  const float C2 = -34.6246810f;   // -24 / ln2

  unsigned wb[4][4];
  float lp0 = 0.f, lp1 = 0.f, lp2 = 0.f, lp3 = 0.f;
#pragma unroll
  for (int nb = 0; nb < 4; ++nb) {
#pragma unroll
    for (int r = 0; r < 4; ++r) {
      float wv = fast_exp2(fmaf(s[nb][r], C1, C2));
      if (diag && (kb + nb * 16 + r > qg)) wv = 0.f;
      wb[nb][r] = __float_as_uint(wv);
      if (nb == 0) lp0 += wv;
      else if (nb == 1) lp1 += wv;
      else if (nb == 2) lp2 += wv;
      else lp3 += wv;
    }
  }
  l += (lp0 + lp1) + (lp2 + lp3);

  // pack pairs along r (v_perm bytes 2,3 of each source = truncated bf16)
  unsigned pk[4][2];
#pragma unroll
  for (int nb = 0; nb < 4; ++nb) {
    pk[nb][0] = __builtin_amdgcn_perm(wb[nb][1], wb[nb][0], 0x07060302u);
    pk[nb][1] = __builtin_amdgcn_perm(wb[nb][3], wb[nb][2], 0x07060302u);
  }

  // redistribute to PV A-frag: 2x permlane32_swap + 2x permlane16_swap per rr
  unsigned Fr[2][4];
#pragma unroll
  for (int rr = 0; rr < 2; ++rr) {
    unsigned a0 = pk[0][rr], a1 = pk[1][rr];
    unsigned a2 = pk[2][rr], a3 = pk[3][rr];
    asm("v_permlane32_swap_b32 %0, %1" : "+v"(a0), "+v"(a1));
    asm("v_permlane32_swap_b32 %0, %1" : "+v"(a2), "+v"(a3));
    asm("v_permlane16_swap_b32 %0, %1" : "+v"(a0), "+v"(a1));
    asm("v_permlane16_swap_b32 %0, %1" : "+v"(a2), "+v"(a3));
    Fr[0][rr] = a0; Fr[0][2 + rr] = a1;
    Fr[1][rr] = a2; Fr[1][2 + rr] = a3;
  }
#pragma unroll
  for (int f = 0; f < 2; ++f) {
    union { unsigned u[4]; short8 s8; } uap;
    uap.u[0] = Fr[f][0]; uap.u[1] = Fr[f][1];
    uap.u[2] = Fr[f][2]; uap.u[3] = Fr[f][3];
    ap[f] = uap.s8;
  }
}

// Fused dual-q-block tile: K/V fragments read ONCE, feed both MFMA chains.
template <bool DUAL>
__device__ __forceinline__ void attn_tile2(
    const short8* aqB, const short8* aqA,
    const unsigned short* sK0, const unsigned short* sK1,
    const unsigned short* sV0, const unsigned short* sV1,
    floatx4* accB, float& lB, floatx4* accA, float& lA,
    const bool diagB, const bool diagA,
    const int qgB, const int qgA, const int kb,
    const int g, const int ml)
{
  floatx4 sB[4], sA[4];
  __builtin_amdgcn_s_setprio(1);
#pragma unroll
  for (int nb = 0; nb < 4; ++nb) {
    short8 bk0 = *(const short8*)(sK0 + (nb * 16 + ml) * 32 + g * 8);
    short8 bk1 = *(const short8*)(sK1 + (nb * 16 + ml) * 32 + g * 8);
    sB[nb] = (floatx4){0.f, 0.f, 0.f, 0.f};
    sB[nb] = __builtin_amdgcn_mfma_f32_16x16x32_bf16(bk0, aqB[0], sB[nb], 0, 0, 0);
    sB[nb] = __builtin_amdgcn_mfma_f32_16x16x32_bf16(bk1, aqB[1], sB[nb], 0, 0, 0);
    if (DUAL) {
      sA[nb] = (floatx4){0.f, 0.f, 0.f, 0.f};
      sA[nb] = __builtin_amdgcn_mfma_f32_16x16x32_bf16(bk0, aqA[0], sA[nb], 0, 0, 0);
      sA[nb] = __builtin_amdgcn_mfma_f32_16x16x32_bf16(bk1, aqA[1], sA[nb], 0, 0, 0);
    }
  }
  __builtin_amdgcn_s_setprio(0);

  short8 apB[2], apA[2];
  softmax_pack(sB, diagB, qgB, kb, lB, apB);
  if (DUAL) softmax_pack(sA, diagA, qgA, kb, lA, apA);

  __builtin_amdgcn_s_setprio(1);
#pragma unroll
  for (int f = 0; f < 2; ++f) {
    const unsigned short* sv = f ? sV1 : sV0;
#pragma unroll
    for (int jd = 0; jd < 4; ++jd) {
      short8 bv = *(const short8*)(sv + (jd * 16 + ml) * 32 + g * 8);
      accB[jd] = __builtin_amdgcn_mfma_f32_16x16x32_bf16(apB[f], bv, accB[jd], 0, 0, 0);
      if (DUAL)
        accA[jd] = __builtin_amdgcn_mfma_f32_16x16x32_bf16(apA[f], bv, accA[jd], 0, 0, 0);
    }
  }
  __builtin_amdgcn_s_setprio(0);
}

__global__ __launch_bounds__(512) void attn_v16(
    const unsigned short* __restrict__ Q,
    const unsigned short* __restrict__ Kg,
    const unsigned short* __restrict__ Vt,
    unsigned short* __restrict__ CTX)
{
  __shared__ AttnLdsU lds;

  // XCD-chunked swizzle (bijective: 512 % 8 == 0): groups 4 consecutive bh
  // per XCD -> K/V working set 2MB < 4MB L2.
  const int L = blockIdx.x;
  const int rid = (L & 7) * 64 + (L >> 3);
  const int p = rid & 15;
  const int bh = rid >> 4;

  const int b = bh >> 4, h = bh & 15;
  const int qbA = p, qbB = 31 - p;
  const int qA0 = qbA * 64, qB0 = qbB * 64;
  const int tid = threadIdx.x, w = tid >> 6, lane = tid & 63;
  const int slice = w & 3, par = w >> 2;
  const int g = lane >> 4, ml = lane & 15;

  const size_t headoff = (size_t)b * S_ * D_ + (size_t)h * HD_;
  const size_t vtoff   = (size_t)bh * HD_ * S_;

  short8 aqA[2], aqB[2];
  {
    const unsigned short* qp =
        Q + headoff + (size_t)(qA0 + slice * 16 + ml) * D_ + g * 8;
    aqA[0] = *(const short8*)qp;
    aqA[1] = *(const short8*)(qp + 32);
  }
  {
    const unsigned short* qp =
        Q + headoff + (size_t)(qB0 + slice * 16 + ml) * D_ + g * 8;
    aqB[0] = *(const short8*)qp;
    aqB[1] = *(const short8*)(qp + 32);
  }

  floatx4 accA[4], accB[4];
#pragma unroll
  for (int jd = 0; jd < 4; ++jd) {
    accA[jd] = (floatx4){0.f, 0.f, 0.f, 0.f};
    accB[jd] = (floatx4){0.f, 0.f, 0.f, 0.f};
  }
  float lA = 0.f, lB = 0.f;
  const int qgA = qA0 + slice * 16 + ml;   // this lane's q-row (A block)
  const int qgB = qB0 + slice * 16 + ml;

  // staging: waves 0-3 handle K, waves 4-7 handle V; each covers 16 rows.
  const int sw = slice;
  const unsigned short* kgb =
      Kg + headoff + (size_t)(sw * 16 + (lane >> 2)) * D_ + (lane & 3) * 8;
  const unsigned short* vgb =
      Vt + vtoff + (size_t)(sw * 16 + (lane >> 2)) * S_ + (lane & 3) * 8;
  const int woff = sw * 512;

  const int ntiles = qbB + 1;

  // ---- stage group 0 into buf 0 (prologue; one unhidden drain) ----
  {
    const int cnt = (ntiles < KTPB) ? ntiles : KTPB;
#pragma unroll
    for (int t = 0; t < KTPB; ++t) {
      if (t >= cnt) break;
      if (w < 4) {
        const size_t ko = (size_t)t * 64 * D_;
        gll16(kgb + ko,      lds.t.k0[0][t] + woff);
        gll16(kgb + ko + 32, lds.t.k1[0][t] + woff);
      } else {
        gll16(vgb + t * 64,      lds.t.v0[0][t] + woff);
        gll16(vgb + t * 64 + 32, lds.t.v1[0][t] + woff);
      }
    }
  }
  __syncthreads();

  for (int kt0 = 0; kt0 < ntiles; kt0 += KTPB) {
    const int bufi = (kt0 >> 1) & 1;
    // ---- stage NEXT group into buf^1 (issue early; drained at barrier) ----
    const int nxt = kt0 + KTPB;
    if (nxt < ntiles) {
      const int cn = (ntiles - nxt < KTPB) ? (ntiles - nxt) : KTPB;
#pragma unroll
      for (int t = 0; t < KTPB; ++t) {
        if (t >= cn) break;
        const int kt = nxt + t;
        if (w < 4) {
          const size_t ko = (size_t)kt * 64 * D_;
          gll16(kgb + ko,      lds.t.k0[bufi ^ 1][t] + woff);
          gll16(kgb + ko + 32, lds.t.k1[bufi ^ 1][t] + woff);
        } else {
          gll16(vgb + kt * 64,      lds.t.v0[bufi ^ 1][t] + woff);
          gll16(vgb + kt * 64 + 32, lds.t.v1[bufi ^ 1][t] + woff);
        }
      }
    }

    // ---- compute current buf (A/B fused when both in causal range) ----
    const int cnt = (ntiles - kt0 < KTPB) ? (ntiles - kt0) : KTPB;  // uniform
    if (par < cnt) {
      const int kt = kt0 + par;
      const int kb = kt * 64 + g * 4;
      if (kt <= qbA)
        attn_tile2<true>(aqB, aqA,
                         lds.t.k0[bufi][par], lds.t.k1[bufi][par],
                         lds.t.v0[bufi][par], lds.t.v1[bufi][par],
                         accB, lB, accA, lA,
                         kt == qbB, kt == qbA, qgB, qgA, kb, g, ml);
      else
        attn_tile2<false>(aqB, aqA,
                          lds.t.k0[bufi][par], lds.t.k1[bufi][par],
                          lds.t.v0[bufi][par], lds.t.v1[bufi][par],
                          accB, lB, accA, lA,
                          kt == qbB, false, qgB, qgA, kb, g, ml);
    }
    __syncthreads();  // drains next-group loads (hidden under compute)
  }

  // ---- combine parity pairs (w, w+4) through LDS ----
  {
    float* slot = lds.comb + (size_t)(slice * 64 + lane) * 36;
    if (par == 1) {
#pragma unroll
      for (int jd = 0; jd < 4; ++jd) {
        *(floatx4*)(slot + jd * 4) = accA[jd];
        *(floatx4*)(slot + 16 + jd * 4) = accB[jd];
      }
      slot[32] = lA;
      slot[33] = lB;
    }
    __syncthreads();
    if (par == 1) return;  // upper waves done; no further barriers below
#pragma unroll
    for (int jd = 0; jd < 4; ++jd) {
      accA[jd] += *(const floatx4*)(slot + jd * 4);
      accB[jd] += *(const floatx4*)(slot + 16 + jd * 4);
    }
    lA += slot[32];
    lB += slot[33];
  }

  // reduce l across the 4 lanes sharing ml (k was spread over g), invert,
  // then fetch per-output-row values (row = g*4+r lives at lane ml=g*4+r).
  lA += __shfl_xor(lA, 16); lA += __shfl_xor(lA, 32);
  lB += __shfl_xor(lB, 16); lB += __shfl_xor(lB, 32);
  const float liA = 1.0f / lA;
  const float liB = 1.0f / lB;
  float lrA[4], lrB[4];
#pragma unroll
  for (int r = 0; r < 4; ++r) {
    lrA[r] = __shfl(liA, g * 4 + r);
    lrB[r] = __shfl(liB, g * 4 + r);
  }

#pragma unroll
  for (int r = 0; r < 4; ++r) {
    const int rowA = qA0 + slice * 16 + g * 4 + r;
    const int rowB = qB0 + slice * 16 + g * 4 + r;
#pragma unroll
    for (int jd = 0; jd < 4; ++jd) {
      CTX[headoff + (size_t)rowA * D_ + jd * 16 + ml] = f2bf(accA[jd][r] * lrA[r]);
      CTX[headoff + (size_t)rowB * D_ + jd * 16 + ml] = f2bf(accB[jd][r] * lrB[r]);
    }
  }
}

// ---------------------------------------------------------------------------
extern "C" void kernel_launch(void* const* d_in, const int* in_sizes, int n_in,
                              void* d_out, int out_size, void* d_ws, size_t ws_size,
                              hipStream_t stream)
{
  const float* X  = (const float*)d_in[0];
  const float* Wq = (const float*)d_in[1];
  const float* Wk = (const float*)d_in[2];
  const float* Wv = (const float*)d_in[3];
  const float* Wo = (const float*)d_in[4];
  const float* bo = (const float*)d_in[5];

  char* ws = (char*)d_ws;
  const size_t MB = 1024 * 1024;

  unsigned short* Qb  = (unsigned short*)(ws);            // 8 MB (CTX aliases)
  unsigned short* Kb  = (unsigned short*)(ws + 8 * MB);   // 8 MB
  unsigned short* Xb  = (unsigned short*)(ws + 16 * MB);  // 8 MB; Vt after QKV
  unsigned short* WT  = (unsigned short*)(ws + 24 * MB);  // WqT|WkT|WvT|WoT
  unsigned short* WoT = WT + (size_t)3 * 1024 * 1024;
  unsigned short* Vb  = (unsigned short*)d_out;           // low 8MB of d_out
  unsigned short* Vt  = Xb;                               // reuse dead Xb

  // merged X-convert (z=4) + 4x W transpose/convert (z=0..3)
  prep_inputs<<<dim3(32, 32, 5), dim3(32, 8), 0, stream>>>(
      X, Xb, Wq, Wk, Wv, Wo, WT);
  // fused Q/K/V projection: Bt = WT[0..3071][1024], BK=64 staging, XCD-swz
  gemm256_qkv<<<dim3(24, 32), 256, 0, stream>>>(Xb, WT, Qb, Kb, Vb);
  // V -> Vt[(b*16+h)*64+d][s]  (Xb dead now)
  transpose_v<<<dim3(64, 2, 32), dim3(32, 8), 0, stream>>>(Vb, Vt);
  // fused A/B, 2-phase pipelined, XCD-swizzled attention; CTX aliases Q
  attn_v16<<<dim3(512), 512, 0, stream>>>(Qb, Kb, Vt, Qb);
  // output projection + bias (64x128 tile, BK=128, 512 blocks, XCD-swz)
  gemm_wo64<<<dim3(8, 64), 256, 0, stream>>>(Qb, WoT, bo, (float*)d_out);
}